// Round 13
// baseline (287.467 us; speedup 1.0000x reference)
//
#include <hip/hip_runtime.h>
#include <math.h>

#define LRELU_A 0.2f
#define NEGBIG (-9.0e15f)

typedef _Float16 f16;
typedef _Float16 f16x8 __attribute__((ext_vector_type(8)));
typedef _Float16 f16x4 __attribute__((ext_vector_type(4)));
typedef float floatx4 __attribute__((ext_vector_type(4)));

__device__ __forceinline__ float rcpf(float x){ return __builtin_amdgcn_rcpf(x); }
__device__ __forceinline__ float sigm(float x){ return rcpf(1.0f+__expf(-x)); }
// Fused GRU gate update, 5 trans ops (exact algebra):
// h' = (1-z)*tanh(u) + z*h = [ (En-1)*Ez + h*(En+1) ] / [ (En+1)*(1+Ez) ]
__device__ __forceinline__ float gru_fuse(float xr, float xz, float xn_pre, float ghn, float h){
    float Er = __expf(-xr);
    float r  = rcpf(1.0f + Er);
    float En = __expf(2.0f*(xn_pre + r*ghn));
    float Ez = __expf(-xz);
    float Dn = En + 1.0f;
    float num = fmaf(h, Dn, (En - 1.0f)*Ez);
    float den = Dn * (1.0f + Ez);
    return num * rcpf(den);
}
__device__ __forceinline__ f16x8 load_cvt8(const float* __restrict__ p){
    float4 a = *(const float4*)p; float4 b = *(const float4*)(p+4);
    f16x8 r; r[0]=(f16)a.x; r[1]=(f16)a.y; r[2]=(f16)a.z; r[3]=(f16)a.w;
    r[4]=(f16)b.x; r[5]=(f16)b.y; r[6]=(f16)b.z; r[7]=(f16)b.w;
    return r;
}
#define MFMA16(A,B,C) __builtin_amdgcn_mfma_f32_16x16x32_f16((A),(B),(C),0,0,0)

// ---------------------------------------------------------------------------
// prep: Wcat1 | WcatA | WTp | fwp | gep | ggp | bucketing (+pos inverse).
// WTp/fwp/gep/ggp are FRAGMENT-MAJOR packed B matrices: addr =
// (frag*64 + lane)*8 + e -> one contiguous 1KB wave read per B-fragment.
// ---------------------------------------------------------------------------
__global__ __launch_bounds__(256) void prep_kernel(
    const float* __restrict__ g1Wih, const float* __restrict__ g1Whh,
    const float* __restrict__ gaWih, const float* __restrict__ gaWhh,
    const float* __restrict__ giW,   const float* __restrict__ fw,
    const float* __restrict__ geW,   const float* __restrict__ ggWih,
    const int* __restrict__ sec,
    f16* __restrict__ Wcat1, f16* __restrict__ WcatA,
    f16* __restrict__ WTp, f16* __restrict__ fwp, f16* __restrict__ gep,
    f16* __restrict__ ggp,
    int* __restrict__ memflat, int* __restrict__ pos,
    int* __restrict__ cnt, int* __restrict__ base)
{
    __shared__ int cs[16], wsc[16];
    const int b = blockIdx.x, tid = threadIdx.x;
    if (b < 160){                      // Wcat1: INF=16, INFPAD=32, KTOT=160
        for (int idx = b*256+tid; idx < 512*160; idx += 160*256){
            int r = idx/160, k = idx - r*160;
            float v = 0.0f;
            if (r < 256){ if (k < 32){ if (k < 16) v = g1Wih[r*16+k]; } else v = g1Whh[r*128 + (k-32)]; }
            else if (r < 384){ if (k < 16) v = g1Wih[r*16+k]; }
            else { if (k >= 32) v = g1Whh[(r-128)*128 + (k-32)]; }
            Wcat1[idx] = (f16)v;
        }
    } else if (b < 416){               // WcatA: INF=128, INFPAD=128, KTOT=256
        for (int idx = (b-160)*256+tid; idx < 512*256; idx += 256*256){
            int r = idx >> 8, k = idx & 255;
            float v = 0.0f;
            if (r < 256){ v = (k < 128) ? gaWih[r*128+k] : gaWhh[r*128 + (k-128)]; }
            else if (r < 384){ if (k < 128) v = gaWih[r*128+k]; }
            else { if (k >= 128) v = gaWhh[(r-128)*128 + (k-128)]; }
            WcatA[idx] = (f16)v;
        }
    } else if (b < 480){               // WTp: giW packed, frag=(jb*4+kb), 16384
        int idx = (b-416)*256+tid;
        int e=idx&7, lane=(idx>>3)&63, fr=idx>>9;
        int kb=fr&3, jb=fr>>2;
        int k = kb*32 + (lane>>4)*8 + e, col = jb*16 + (lane&15);
        WTp[idx] = (f16)giW[k*128 + col];
    } else if (b < 672){               // fwp: fw packed, frag=(jb*12+kb), 49152
        int idx = (b-480)*256+tid;
        int e=idx&7, lane=(idx>>3)&63, fr=idx>>9;
        int kb=fr%12, jb=fr/12;
        int k = kb*32 + (lane>>4)*8 + e, col = jb*16 + (lane&15);
        fwp[idx] = (f16)fw[k*128 + col];
    } else if (b < 736){               // gep: geW packed, frag=(jb*4+kb), 16384
        int idx = (b-672)*256+tid;
        int e=idx&7, lane=(idx>>3)&63, fr=idx>>9;
        int kb=fr&3, jb=fr>>2;
        int k = kb*32 + (lane>>4)*8 + e, col = jb*16 + (lane&15);
        gep[idx] = (f16)geW[k*128 + col];
    } else if (b < 928){               // ggp: ggWih packed, frag=((G*8+jb)*4+kb), 49152
        int idx = (b-736)*256+tid;
        int e=idx&7, lane=(idx>>3)&63, fr=idx>>9;
        int kb=fr&3, jb=(fr>>2)&7, G=fr>>5;
        int row = G*128 + jb*16 + (lane&15), k = kb*32 + (lane>>4)*8 + e;
        ggp[idx] = (f16)ggWih[row*128 + k];
    } else {                           // bucket + inverse permutation
        if (tid < 16) cs[tid] = 0;
        __syncthreads();
        for (int s = tid; s < 2048; s += 256) atomicAdd(&cs[sec[s]], 1);
        __syncthreads();
        if (tid == 0){
            int acc = 0;
            for (int g=0; g<16; g++){ cnt[g]=cs[g]; base[g]=acc; wsc[g]=acc; acc+=cs[g]; }
        }
        __syncthreads();
        for (int s = tid; s < 2048; s += 256){
            int g = sec[s];
            int p = atomicAdd(&wsc[g], 1);
            memflat[p] = s;
            pos[s] = p;
        }
    }
}

// ---------------------------------------------------------------------------
// Short GRU+attn — R9-proven config (83.6us): M=32, 8 waves, 512 thr,
// 96 VGPR no spill, 8 tiles/block (1 round, 1 prologue/CU), x reg-prefetch.
// R10: 1024-thread blocks cannot escape the 64-VGPR cap (all knobs ignored).
// ---------------------------------------------------------------------------
__global__ __launch_bounds__(512,2) void gru_short(
    const float* __restrict__ x, const f16* __restrict__ Wcat,
    const float* __restrict__ bih, const float* __restrict__ bhh,
    const float* __restrict__ aw, const float* __restrict__ ab,
    f16* __restrict__ out)
{
    __shared__ __align__(16) f16 xs[5][32][40];
    __shared__ __align__(16) f16 hs[2][32][136];
    __shared__ float scpart[2][8][32];
    const int tid = threadIdx.x, w = tid>>6, lane = tid&63;
    const int c = lane&15, quad = lane>>4;

    { f16x4 z4 = {0,0,0,0};
      f16x4* zx = (f16x4*)&xs[0][0][0];
      for (int i=tid; i<1600; i+=512) zx[i] = z4; }

    const int jrow = w*16 + c;
    f16x8 Ar[5], Az[5], Agi, Agh[4];
#pragma unroll
    for (int kb=0;kb<5;kb++){
        Ar[kb] = *(const f16x8*)&Wcat[(size_t)(jrow)*160 + kb*32 + quad*8];
        Az[kb] = *(const f16x8*)&Wcat[(size_t)(128+jrow)*160 + kb*32 + quad*8];
    }
    Agi = *(const f16x8*)&Wcat[(size_t)(256+jrow)*160 + quad*8];
#pragma unroll
    for (int i=0;i<4;i++)
        Agh[i] = *(const f16x8*)&Wcat[(size_t)(384+jrow)*160 + 32 + i*32 + quad*8];

    float brz_r[4], brz_z[4], b_in[4], b_hn[4], awr[4];
#pragma unroll
    for (int r=0;r<4;r++){
        int j = w*16 + quad*4 + r;
        brz_r[r] = bih[j] + bhh[j];
        brz_z[r] = bih[128+j] + bhh[128+j];
        b_in[r] = bih[256+j]; b_hn[r] = bhh[256+j];
        awr[r] = aw[j];
    }
    const float abv = ab[0];

    const int s0i = tid/20,        q0 = tid - 20*s0i;
    const int i1  = tid + 512;
    const int s1i = i1/20,         q1 = i1 - 20*s1i;
    const bool pf1 = (tid < 128);
    float4 xpf0, xpf1;
    {
        const size_t base0 = (size_t)(blockIdx.x*8)*32;
        xpf0 = *(const float4*)&x[(base0 + s0i)*80 + q0*4];
        if (pf1) xpf1 = *(const float4*)&x[(base0 + s1i)*80 + q1*4];
    }

#pragma unroll 1
    for (int tile=0; tile<8; ++tile){
        const int s0 = (blockIdx.x*8 + tile)*32;
        { f16x4 z4 = {0,0,0,0};
          f16x4* zh = (f16x4*)&hs[1][0][0];
          for (int i=tid; i<1088; i+=512) zh[i] = z4; }
        {
            int t = (q0*4)>>4, f = (q0*4)&15;
            f16x4 h4; h4[0]=(f16)xpf0.x; h4[1]=(f16)xpf0.y; h4[2]=(f16)xpf0.z; h4[3]=(f16)xpf0.w;
            *(f16x4*)&xs[t][s0i][f] = h4;
            if (pf1){
                int t1 = (q1*4)>>4, f1 = (q1*4)&15;
                f16x4 g4; g4[0]=(f16)xpf1.x; g4[1]=(f16)xpf1.y; g4[2]=(f16)xpf1.z; g4[3]=(f16)xpf1.w;
                *(f16x4*)&xs[t1][s1i][f1] = g4;
            }
        }
        if (tile < 7){
            const size_t basen = (size_t)(s0 + 32);
            xpf0 = *(const float4*)&x[(basen + s0i)*80 + q0*4];
            if (pf1) xpf1 = *(const float4*)&x[(basen + s1i)*80 + q1*4];
        }
        float hreg[2][4], aacc[2][4], l_[2] = {0.0f, 0.0f};
#pragma unroll
        for (int st=0; st<2; st++)
#pragma unroll
            for (int r=0;r<4;r++){ hreg[st][r]=0.0f; aacc[st][r]=0.0f; }
        __syncthreads();

#pragma unroll 1
        for (int t=0; t<5; ++t){
            const int rp = (t&1)^1, wp = t&1;
            f16x8 Bx[2], Bh[2][4];
#pragma unroll
            for (int st=0; st<2; st++){
                Bx[st] = *(const f16x8*)&xs[t][st*16+c][quad*8];
#pragma unroll
                for (int i=0;i<4;i++)
                    Bh[st][i] = *(const f16x8*)&hs[rp][st*16+c][i*32+quad*8];
            }
            if (t > 0){
#pragma unroll
                for (int st=0; st<2; st++){
                    float sc = abv;
#pragma unroll
                    for (int ww=0; ww<8; ww++) sc += scpart[rp][ww][st*16+c];
                    float e = __expf(sc);
                    l_[st] += e;
#pragma unroll
                    for (int r=0;r<4;r++) aacc[st][r] += e*hreg[st][r];
                }
            }
            float sp[2];
#pragma unroll
            for (int st=0; st<2; st++){
                floatx4 ar = {0,0,0,0}, az = {0,0,0,0}, agi = {0,0,0,0}, agh = {0,0,0,0};
                ar = MFMA16(Ar[0], Bx[st], ar);
                az = MFMA16(Az[0], Bx[st], az);
                agi = MFMA16(Agi, Bx[st], agi);
#pragma unroll
                for (int i=0;i<4;i++){
                    ar = MFMA16(Ar[1+i], Bh[st][i], ar);
                    az = MFMA16(Az[1+i], Bh[st][i], az);
                    agh = MFMA16(Agh[i], Bh[st][i], agh);
                }
                f16x4 h4;
                sp[st] = 0.0f;
#pragma unroll
                for (int r=0;r<4;r++){
                    float hn = gru_fuse(ar[r] + brz_r[r], az[r] + brz_z[r],
                                        agi[r] + b_in[r], agh[r] + b_hn[r], hreg[st][r]);
                    hreg[st][r] = hn; h4[r] = (f16)hn;
                    sp[st] += hn * awr[r];
                }
                *(f16x4*)&hs[wp][st*16 + c][w*16 + quad*4] = h4;
            }
#pragma unroll
            for (int st=0; st<2; st++){
                sp[st] += __shfl_xor(sp[st], 16);
                sp[st] += __shfl_xor(sp[st], 32);
            }
            if (lane < 16){ scpart[wp][w][lane] = sp[0]; scpart[wp][w][16+lane] = sp[1]; }
            __syncthreads();
        }
#pragma unroll
        for (int st=0; st<2; st++){
            float sc = abv;
#pragma unroll
            for (int ww=0; ww<8; ww++) sc += scpart[0][ww][st*16+c];
            float e = __expf(sc);
            l_[st] += e;
            float inv = rcpf(l_[st]);
            f16x4 h4;
#pragma unroll
            for (int r=0;r<4;r++) h4[r] = (f16)((aacc[st][r] + e*hreg[st][r])*inv);
            *(f16x4*)&hs[0][st*16 + c][w*16 + quad*4] = h4;
        }
        __syncthreads();
        { int s = tid>>4, p = tid&15;
          *(f16x8*)&out[(size_t)(s0+s)*128 + p*8] = *(const f16x8*)&hs[0][s][p*8]; }
    }
}

// ---------------------------------------------------------------------------
// Merged: blocks 0..255 = la GRU+attn (T=32, M=8); blocks 256..319 = gat_prep.
// gru_la now software-pipelines the x-projection: 12 of 24 MFMAs/step are
// x-only (independent of the recurrence) — computed one step AHEAD (xg_next)
// while the h-chain of the current step stalls. Triple-buffered xs; exact
// same accumulation order (Bx i=0..3 then Bh i=0..3) -> identical numerics.
// ---------------------------------------------------------------------------
__global__ __launch_bounds__(512,2) void gru_la_gatprep(
    const f16* __restrict__ xseq, const f16* __restrict__ Wcat,
    const float* __restrict__ bih, const float* __restrict__ bhh,
    const float* __restrict__ aw, const float* __restrict__ ab,
    f16* __restrict__ out,
    const f16* __restrict__ WTp, const float* __restrict__ gia,
    const int* __restrict__ memflat,
    f16* __restrict__ Whs, float* __restrict__ ers, float* __restrict__ el)
{
    __shared__ __align__(16) f16 xs[3][16][136];
    __shared__ __align__(16) f16 hs[2][16][136];
    __shared__ float scpart[2][8][16];
    __shared__ __align__(16) float tbuf[32][132];
    __shared__ int rows[32];
    const int tid = threadIdx.x, w = tid>>6, lane = tid&63;
    const int c = lane&15, quad = lane>>4;

    if (blockIdx.x >= 256){
        // ---------------- gat_prep (8 waves, 1 jb per wave) ----------------
        const int p0 = (blockIdx.x-256)*32;
        if (tid < 32) rows[tid] = memflat[p0 + tid];
        __syncthreads();
        f16x8 A[2][4];
#pragma unroll
        for (int mt=0;mt<2;mt++)
#pragma unroll
            for (int kb=0;kb<4;kb++)
                A[mt][kb] = *(const f16x8*)&xseq[((size_t)rows[mt*16+c]*32 + 31)*128 + kb*32 + quad*8];
        {
            f16x8 B[4];
#pragma unroll
            for (int kb=0;kb<4;kb++)
                B[kb] = *(const f16x8*)&WTp[(((size_t)(w*4+kb))*64 + lane)*8];
            floatx4 acc[2] = {{0,0,0,0},{0,0,0,0}};
#pragma unroll
            for (int kb=0;kb<4;kb++){
                acc[0] = MFMA16(A[0][kb], B[kb], acc[0]);
                acc[1] = MFMA16(A[1][kb], B[kb], acc[1]);
            }
#pragma unroll
            for (int mt=0;mt<2;mt++)
#pragma unroll
                for (int r=0;r<4;r++)
                    tbuf[mt*16 + quad*4 + r][w*16 + c] = acc[mt][r];
        }
        __syncthreads();
        for (int i=tid; i<1024; i+=512){
            int s = i>>5, p = i&31;
            float4 v = *(const float4*)&tbuf[s][p*4];
            f16x4 h4; h4[0]=(f16)v.x; h4[1]=(f16)v.y; h4[2]=(f16)v.z; h4[3]=(f16)v.w;
            *(f16x4*)&Whs[(size_t)(p0+s)*128 + p*4] = h4;
        }
        for (int k=0; k<4; k++){
            int row = w*4 + k;
            float w0 = tbuf[row][lane], w1 = tbuf[row][64+lane];
            float v1 = w0*gia[lane]     + w1*gia[64+lane];
            float v2 = w0*gia[128+lane] + w1*gia[192+lane];
#pragma unroll
            for (int off=32; off; off>>=1){ v1 += __shfl_down(v1,off); v2 += __shfl_down(v2,off); }
            if (lane==0){ el[rows[row]] = v1; ers[p0+row] = v2; }
        }
        return;
    }
    // ------------------------------ gru_la ------------------------------
    const int s0 = blockIdx.x*8;
    { f16x4 z4 = {0,0,0,0};
      f16x4* za = (f16x4*)&xs[0][0][0];
      for (int i=tid; i<1632; i+=512) za[i] = z4;
      f16x4* zh = (f16x4*)&hs[0][0][0];
      for (int i=tid; i<1088; i+=512) zh[i] = z4; }
    __syncthreads();
    // stage x[0] -> buf0 and x[1] -> buf1
    if (tid < 256){
        int half = tid>>7, r = tid&127;
        int s = r>>4, p = r&15;
        *(f16x8*)&xs[half][s][p*8] = *(const f16x8*)&xseq[((size_t)(s0+s)*32 + half)*128 + p*8];
    }
    const int jrow = w*16 + c;
    f16x8 Ar[8], Az[8], Agi[4], Agh[4];
#pragma unroll
    for (int kb=0;kb<8;kb++){
        Ar[kb] = *(const f16x8*)&Wcat[(size_t)(jrow)*256 + kb*32 + quad*8];
        Az[kb] = *(const f16x8*)&Wcat[(size_t)(128+jrow)*256 + kb*32 + quad*8];
    }
#pragma unroll
    for (int i=0;i<4;i++){
        Agi[i] = *(const f16x8*)&Wcat[(size_t)(256+jrow)*256 + i*32 + quad*8];
        Agh[i] = *(const f16x8*)&Wcat[(size_t)(384+jrow)*256 + 128 + i*32 + quad*8];
    }
    float brz_r[4], brz_z[4], b_in[4], b_hn[4], awr[4];
#pragma unroll
    for (int r=0;r<4;r++){
        int j = w*16 + quad*4 + r;
        brz_r[r] = bih[j] + bhh[j];
        brz_z[r] = bih[128+j] + bhh[128+j];
        b_in[r] = bih[256+j]; b_hn[r] = bhh[256+j];
        awr[r] = aw[j];
    }
    const float abv = ab[0];
    float hreg[4] = {0,0,0,0}, aacc[4] = {0,0,0,0}, l_ = 0.0f;
    __syncthreads();

    // xg for step 0 (from buf0)
    floatx4 xar = {0,0,0,0}, xaz = {0,0,0,0}, xagi = {0,0,0,0};
    {
        f16x8 Bx0[4];
#pragma unroll
        for (int i=0;i<4;i++) Bx0[i] = *(const f16x8*)&xs[0][c][i*32+quad*8];
#pragma unroll
        for (int i=0;i<4;i++){
            xar  = MFMA16(Ar[i],  Bx0[i], xar);
            xaz  = MFMA16(Az[i],  Bx0[i], xaz);
            xagi = MFMA16(Agi[i], Bx0[i], xagi);
        }
    }

#pragma unroll 1
    for (int t=0; t<32; ++t){
        const int rp = (t&1)^1, wp = t&1;
        f16x8 Bh[4];
#pragma unroll
        for (int i=0;i<4;i++)
            Bh[i] = *(const f16x8*)&hs[rp][c][i*32+quad*8];
        // pipelined x-projection for step t+1 (independent of h-chain)
        floatx4 nar = {0,0,0,0}, naz = {0,0,0,0}, nagi = {0,0,0,0};
        if (t < 31){
            const f16* xb = &xs[(t+1)%3][0][0];
            f16x8 Bxn[4];
#pragma unroll
            for (int i=0;i<4;i++)
                Bxn[i] = *(const f16x8*)&xb[(size_t)c*136 + i*32 + quad*8];
#pragma unroll
            for (int i=0;i<4;i++){
                nar  = MFMA16(Ar[i],  Bxn[i], nar);
                naz  = MFMA16(Az[i],  Bxn[i], naz);
                nagi = MFMA16(Agi[i], Bxn[i], nagi);
            }
        }
        f16x8 xstage;
        const bool do_stage = (t < 30) && (tid < 128);
        if (do_stage){
            int s = tid>>4, p = tid&15;
            xstage = *(const f16x8*)&xseq[((size_t)(s0+s)*32 + t+2)*128 + p*8];
        }
        if (t > 0){
            float sc = abv;
#pragma unroll
            for (int ww=0; ww<8; ww++) sc += scpart[rp][ww][c];
            float e = __expf(sc);
            l_ += e;
#pragma unroll
            for (int r=0;r<4;r++) aacc[r] += e*hreg[r];
        }
        // h-MFMAs: accumulate onto the precomputed x-projection (same order)
        floatx4 ar = xar, az = xaz, agh = {0,0,0,0};
#pragma unroll
        for (int i=0;i<4;i++){
            ar  = MFMA16(Ar[4+i], Bh[i], ar);
            az  = MFMA16(Az[4+i], Bh[i], az);
            agh = MFMA16(Agh[i],  Bh[i], agh);
        }
        f16x4 h4;
        float sp = 0.0f;
#pragma unroll
        for (int r=0;r<4;r++){
            float hn = gru_fuse(ar[r] + brz_r[r], az[r] + brz_z[r],
                                xagi[r] + b_in[r], agh[r] + b_hn[r], hreg[r]);
            hreg[r] = hn; h4[r] = (f16)hn;
            sp += hn * awr[r];
        }
        *(f16x4*)&hs[wp][c][w*16 + quad*4] = h4;
        if (do_stage){
            int s = tid>>4, p = tid&15;
            *(f16x8*)&xs[(t+2)%3][s][p*8] = xstage;
        }
        sp += __shfl_xor(sp, 16);
        sp += __shfl_xor(sp, 32);
        if (lane < 16) scpart[wp][w][lane] = sp;
        __syncthreads();
        xar = nar; xaz = naz; xagi = nagi;
    }
    // drain (t=31 wrote scpart[1])
    {
        float sc = abv;
#pragma unroll
        for (int ww=0; ww<8; ww++) sc += scpart[1][ww][c];
        float e = __expf(sc);
        l_ += e;
        float inv = rcpf(l_);
        f16x4 h4;
#pragma unroll
        for (int r=0;r<4;r++) h4[r] = (f16)((aacc[r] + e*hreg[r])*inv);
        *(f16x4*)&hs[1][c][w*16 + quad*4] = h4;
    }
    __syncthreads();
    if (tid < 128){
        int s = tid>>4, p = tid&15;
        *(f16x8*)&out[(size_t)(s0+s)*128 + p*8] = *(const f16x8*)&hs[1][s][p*8];
    }
}

// ---------------------------------------------------------------------------
// GAT intra, member-list. One wave per row; streams sorted f16 Wh.
// ---------------------------------------------------------------------------
__global__ __launch_bounds__(256) void gat_intra_mem_kernel(
    const f16* __restrict__ Whs, const float* __restrict__ ers,
    const float* __restrict__ el, const int* __restrict__ sec,
    const int* __restrict__ cnt, const int* __restrict__ base,
    f16* __restrict__ outp, int S)
{
    int wave = threadIdx.x>>6, lane = threadIdx.x&63;
    int i = blockIdx.x*4 + wave;
    if (i>=S) return;
    int g = sec[i];
    int n = cnt[g], b = base[g];
    float eli = el[i];
    float m = -INFINITY;
    for (int jj=lane; jj<n; jj+=64){
        float v = eli + ers[b+jj]; v = v>0.f? v : LRELU_A*v;
        m = fmaxf(m, v);
    }
#pragma unroll
    for (int off=32; off; off>>=1) m = fmaxf(m, __shfl_xor(m, off));
    float l = 0.f, c0=0.f, c1=0.f;
#pragma unroll 4
    for (int jj=0; jj<n; jj++){
        float v = eli + ers[b+jj]; v = v>0.f? v : LRELU_A*v;
        float p = __expf(v-m);
        l += p;
        c0 += p*(float)Whs[(size_t)(b+jj)*128 + lane];
        c1 += p*(float)Whs[(size_t)(b+jj)*128 + 64 + lane];
    }
    float il = rcpf(l);
    c0 *= il; c1 *= il;
    outp[(size_t)i*128+lane]    = (f16)(c0>0.f? c0 : expm1f(c0));
    outp[(size_t)i*128+64+lane] = (f16)(c1>0.f? c1 : expm1f(c1));
}

// ---------------------------------------------------------------------------
// lg: T=1 GRU via MFMA; B from ggp (fragment-packed f16).
// Writes orig-order lg16 and sorted lgs.
// ---------------------------------------------------------------------------
__global__ __launch_bounds__(256) void lg_mfma(
    const f16* __restrict__ intra16, const f16* __restrict__ ggp,
    const float* __restrict__ bih, const float* __restrict__ bhh,
    const int* __restrict__ pos,
    f16* __restrict__ lgout, f16* __restrict__ lgs)
{
    __shared__ __align__(16) f16 tbuf[32][136];
    const int tid = threadIdx.x, w = tid>>6, lane = tid&63;
    const int c = lane&15, quad = lane>>4;
    const int s0 = blockIdx.x*32;
    f16x8 A[2][4];
#pragma unroll
    for (int mt=0;mt<2;mt++)
#pragma unroll
        for (int kb=0;kb<4;kb++)
            A[mt][kb] = *(const f16x8*)&intra16[(size_t)(s0+mt*16+c)*128 + kb*32 + quad*8];
#pragma unroll
    for (int i=0;i<2;i++){
        int jb = w*2 + i;
        int j = jb*16 + c;
        f16x8 Br[4], Bz[4], Bn[4];
#pragma unroll
        for (int kb=0;kb<4;kb++){
            Br[kb] = *(const f16x8*)&ggp[(((size_t)((0*8+jb)*4+kb))*64 + lane)*8];
            Bz[kb] = *(const f16x8*)&ggp[(((size_t)((1*8+jb)*4+kb))*64 + lane)*8];
            Bn[kb] = *(const f16x8*)&ggp[(((size_t)((2*8+jb)*4+kb))*64 + lane)*8];
        }
        float b_r = bih[j] + bhh[j];
        float b_z = bih[128+j] + bhh[128+j];
        float b_i = bih[256+j], b_h = bhh[256+j];
        floatx4 ar[2] = {{0,0,0,0},{0,0,0,0}};
        floatx4 az[2] = {{0,0,0,0},{0,0,0,0}};
        floatx4 an[2] = {{0,0,0,0},{0,0,0,0}};
#pragma unroll
        for (int kb=0;kb<4;kb++)
#pragma unroll
            for (int mt=0;mt<2;mt++){
                ar[mt] = MFMA16(A[mt][kb], Br[kb], ar[mt]);
                az[mt] = MFMA16(A[mt][kb], Bz[kb], az[mt]);
                an[mt] = MFMA16(A[mt][kb], Bn[kb], an[mt]);
            }
#pragma unroll
        for (int mt=0;mt<2;mt++)
#pragma unroll
            for (int r=0;r<4;r++){
                float Er = __expf(-(ar[mt][r] + b_r));
                float rg = rcpf(1.0f + Er);
                float En = __expf(2.0f*(an[mt][r] + b_i + rg*b_h));
                float Ez = __expf(-(az[mt][r] + b_z));
                float v = (En - 1.0f)*Ez * rcpf((En + 1.0f)*(1.0f + Ez));
                tbuf[mt*16 + quad*4 + r][j] = (f16)v;
            }
    }
    __syncthreads();
    for (int i=tid; i<512; i+=256){
        int s = i>>4, p = i&15;
        f16x8 v = *(const f16x8*)&tbuf[s][p*8];
        *(f16x8*)&lgout[(size_t)(s0+s)*128 + p*8] = v;
        *(f16x8*)&lgs[(size_t)pos[s0+s]*128 + p*8] = v;
    }
}

// ---------------------------------------------------------------------------
// Fused tail: sector means (sorted lgs, contiguous) + inter GAT.
// Phase B via MFMA with gep (fragment-packed).
// ---------------------------------------------------------------------------
__global__ __launch_bounds__(1024) void gat_inter_fused(
    const f16* __restrict__ lgs, const int* __restrict__ cnt,
    const int* __restrict__ base, const int* __restrict__ adj,
    const f16* __restrict__ gep, const float* __restrict__ a,
    float* __restrict__ outp)
{
    __shared__ __align__(16) float hs[16][132];
    __shared__ __align__(16) float Whs[16][132];
    __shared__ float el[16], er[16];
    __shared__ float att[16][16];
    const int tid = threadIdx.x, w = tid>>6, lane = tid&63;
    const int c = lane&15, quad = lane>>4;

    // Phase A: wave w sums sector w over its contiguous sorted rows.
    {
        int n = cnt[w], b = base[w];
        const int rowoff = lane>>4;
        const int colb = (lane&15)*8;
        float acc[8] = {0,0,0,0,0,0,0,0};
        for (int r = rowoff; r < n; r += 4){
            f16x8 v = *(const f16x8*)&lgs[(size_t)(b+r)*128 + colb];
#pragma unroll
            for (int k=0;k<8;k++) acc[k] += (float)v[k];
        }
#pragma unroll
        for (int k=0;k<8;k++){
            acc[k] += __shfl_xor(acc[k], 16);
            acc[k] += __shfl_xor(acc[k], 32);
        }
        if (lane < 16){
            float inv = rcpf(fmaxf((float)n, 1.0f));
#pragma unroll
            for (int k=0;k<8;k++) hs[w][colb+k] = acc[k]*inv;
        }
    }
    __syncthreads();
    // Phase B (MFMA): Whs = hs @ geW; wave w<8 computes column tile w.
    if (w < 8){
        f16x8 A[4], B[4];
#pragma unroll
        for (int kb=0;kb<4;kb++){
            A[kb] = load_cvt8(&hs[c][kb*32 + quad*8]);
            B[kb] = *(const f16x8*)&gep[(((size_t)(w*4+kb))*64 + lane)*8];
        }
        floatx4 acc = {0,0,0,0};
#pragma unroll
        for (int kb=0;kb<4;kb++) acc = MFMA16(A[kb], B[kb], acc);
#pragma unroll
        for (int r=0;r<4;r++) Whs[quad*4 + r][w*16 + c] = acc[r];
    }
    __syncthreads();
    // Phase C: el/er — wave w reduces sector w; lanes 0-31: el, 32-63: er.
    {
        int half = lane>>5, l = lane&31;
        const float* av = a + half*128;
        float acc2 = 0.f;
#pragma unroll
        for (int k=0;k<4;k++) acc2 += Whs[w][l+32*k]*av[l+32*k];
#pragma unroll
        for (int off=1; off<32; off<<=1) acc2 += __shfl_xor(acc2, off);
        if (l==0){ if (half) er[w]=acc2; else el[w]=acc2; }
    }
    __syncthreads();
    // Phase D: 16x16 masked softmax
    if (tid<16){
        int i=tid; float m=NEGBIG; float e[16];
        for(int j=0;j<16;j++){
            float v = el[i]+er[j]; v = v>0.f? v : LRELU_A*v;
            e[j] = (adj[i*16+j]>0)? v : NEGBIG;
            m = fmaxf(m,e[j]);
        }
        float l=0.f;
        for(int j=0;j<16;j++){ float p=__expf(e[j]-m); att[i][j]=p; l+=p; }
        float il = rcpf(l);
        for(int j=0;j<16;j++) att[i][j] *= il;
    }
    __syncthreads();
    // Phase E: att @ Whs + ELU
#pragma unroll
    for (int i=0;i<2;i++){
        int idx=i*1024+tid; int o=idx&127, s=idx>>7;
        float acc=0.f;
#pragma unroll
        for(int j=0;j<16;j++) acc += att[s][j]*Whs[j][o];
        outp[s*128+o] = acc>0.f? acc : expm1f(acc);
    }
}

// ---------------------------------------------------------------------------
// fused = [lg|la|sec_ps] @ fw + fb, then both heads. B from fwp (packed).
// ---------------------------------------------------------------------------
__global__ __launch_bounds__(256) void fused_mfma(
    const f16* __restrict__ lg16, const f16* __restrict__ la16,
    const float* __restrict__ seco, const int* __restrict__ sec,
    const f16* __restrict__ fwp,
    const float* __restrict__ fb, const float* __restrict__ rw,
    const float* __restrict__ rb, const float* __restrict__ mw,
    const float* __restrict__ mb, float* __restrict__ outp)
{
    __shared__ float rpart[4][32], mpart[4][32];
    const int tid = threadIdx.x, w = tid>>6, lane = tid&63;
    const int c = lane&15, quad = lane>>4;
    const int s0 = blockIdx.x*32;
    f16x8 A[2][12];
#pragma unroll
    for (int mt=0;mt<2;mt++){
        int row = s0 + mt*16 + c;
        int g = sec[row];
#pragma unroll
        for (int kb=0;kb<4;kb++){
            A[mt][kb]   = *(const f16x8*)&lg16[(size_t)row*128 + kb*32 + quad*8];
            A[mt][4+kb] = *(const f16x8*)&la16[(size_t)row*128 + kb*32 + quad*8];
            A[mt][8+kb] = load_cvt8(&seco[(size_t)g*128 + kb*32 + quad*8]);
        }
    }
    float rsum[2][4] = {{0,0,0,0},{0,0,0,0}};
    float msum[2][4] = {{0,0,0,0},{0,0,0,0}};
#pragma unroll
    for (int i=0;i<2;i++){
        int jb = w*2 + i;
        int col = jb*16 + c;
        f16x8 B[12];
#pragma unroll
        for (int kb=0;kb<12;kb++)
            B[kb] = *(const f16x8*)&fwp[(((size_t)(jb*12+kb))*64 + lane)*8];
        floatx4 acc[2] = {{0,0,0,0},{0,0,0,0}};
#pragma unroll
        for (int kb=0;kb<12;kb++){
            acc[0] = MFMA16(A[0][kb], B[kb], acc[0]);
            acc[1] = MFMA16(A[1][kb], B[kb], acc[1]);
        }
        float fbv = fb[col], rwv = rw[col], mwv = mw[col];
#pragma unroll
        for (int mt=0;mt<2;mt++)
#pragma unroll
            for (int r=0;r<4;r++){
                float fu = acc[mt][r] + fbv;
                rsum[mt][r] += fu*rwv;
                msum[mt][r] += fu*mwv;
            }
    }
#pragma unroll
    for (int mt=0;mt<2;mt++)
#pragma unroll
        for (int r=0;r<4;r++){
#pragma unroll
            for (int off=1; off<16; off<<=1){
                rsum[mt][r] += __shfl_xor(rsum[mt][r], off);
                msum[mt][r] += __shfl_xor(msum[mt][r], off);
            }
            if (c==0){
                rpart[w][mt*16 + quad*4 + r] = rsum[mt][r];
                mpart[w][mt*16 + quad*4 + r] = msum[mt][r];
            }
        }
    __syncthreads();
    if (tid < 32){
        int s = tid;
        float rs = rb[0], ms = mb[0];
#pragma unroll
        for (int ww=0; ww<4; ww++){ rs += rpart[ww][s]; ms += mpart[ww][s]; }
        outp[s0+s] = rs;
        outp[2048 + s0 + s] = sigm(ms);
    }
}

extern "C" void kernel_launch(void* const* d_in, const int* in_sizes, int n_in,
                              void* d_out, int out_size, void* d_ws, size_t ws_size,
                              hipStream_t stream) {
    const float* sf    = (const float*)d_in[0];
    const int*   sec   = (const int*)  d_in[1];
    const int*   adj   = (const int*)  d_in[2];
    const float* g1Wih = (const float*)d_in[3];
    const float* g1Whh = (const float*)d_in[4];
    const float* g1bih = (const float*)d_in[5];
    const float* g1bhh = (const float*)d_in[6];
    const float* a1w   = (const float*)d_in[7];
    const float* a1b   = (const float*)d_in[8];
    const float* giW   = (const float*)d_in[9];
    const float* gia   = (const float*)d_in[10];
    const float* ggWih = (const float*)d_in[11];
    const float* ggbih = (const float*)d_in[13];
    const float* ggbhh = (const float*)d_in[14];
    const float* gaWih = (const float*)d_in[17];
    const float* gaWhh = (const float*)d_in[18];
    const float* gabih = (const float*)d_in[19];
    const float* gabhh = (const float*)d_in[20];
    const float* aaw   = (const float*)d_in[21];
    const float* aab   = (const float*)d_in[22];
    const float* geW   = (const float*)d_in[23];
    const float* gea   = (const float*)d_in[24];
    const float* fw    = (const float*)d_in[25];
    const float* fb    = (const float*)d_in[26];
    const float* rw    = (const float*)d_in[27];
    const float* rb    = (const float*)d_in[28];
    const float* mw    = (const float*)d_in[29];
    const float* mb    = (const float*)d_in[30];

    char* p = (char*)d_ws;
    f16*   shrt16 = (f16*)p;   p += (size_t)65536*128*2;
    f16*   intra16= (f16*)p;   p += (size_t)262144*2;
    f16*   lg16   = (f16*)p;   p += (size_t)262144*2;
    f16*   la16   = (f16*)p;   p += (size_t)262144*2;
    f16*   Whs    = (f16*)p;   p += (size_t)262144*2;
    f16*   lgs    = (f16*)p;   p += (size_t)262144*2;
    f16*   Wcat1  = (f16*)p;   p += (size_t)512*160*2;
    f16*   WcatA  = (f16*)p;   p += (size_t)512*256*2;
    f16*   WTp    = (f16*)p;   p += (size_t)16384*2;
    f16*   gep    = (f16*)p;   p += (size_t)16384*2;
    f16*   fwp    = (f16*)p;   p += (size_t)49152*2;
    f16*   ggp    = (f16*)p;   p += (size_t)49152*2;
    float* el     = (float*)p; p += 2048*4;
    float* ers    = (float*)p; p += 2048*4;
    float* seco   = (float*)p; p += 2048*4;
    int*   memflat= (int*)p;   p += 2048*4;
    int*   pos    = (int*)p;   p += 2048*4;
    int*   cnt    = (int*)p;   p += 16*4;
    int*   basep  = (int*)p;   p += 16*4;

    // 0. all weight prep (fragment-packed B matrices) + bucketing
    prep_kernel<<<929,256,0,stream>>>(g1Wih, g1Whh, gaWih, gaWhh, giW, fw, geW, ggWih, sec,
                                      Wcat1, WcatA, WTp, fwp, gep, ggp,
                                      memflat, pos, cnt, basep);
    // 1. short GRU+attn — R9 config: 8 waves, 8 tiles/block, x-prefetch
    gru_short<<<256,512,0,stream>>>(sf, Wcat1, g1bih, g1bhh, a1w, a1b, shrt16);
    // 2. la GRU+attn (x-proj pipelined) || gat_prep — merged
    gru_la_gatprep<<<320,512,0,stream>>>(shrt16, WcatA, gabih, gabhh, aaw, aab, la16,
                                         WTp, gia, memflat, Whs, ers, el);
    // 3. intra-sector GAT
    gat_intra_mem_kernel<<<512,256,0,stream>>>(Whs, ers, el, sec, cnt, basep, intra16, 2048);
    // 4. lg (T=1 simplification) — ggp packed B; also emits sorted lgs
    lg_mfma<<<64,256,0,stream>>>(intra16, ggp, ggbih, ggbhh, pos, lg16, lgs);
    // 5+6. fused sector means + inter-sector GAT (phase B via MFMA + gep)
    gat_inter_fused<<<1,1024,0,stream>>>(lgs, cnt, basep, adj, gep, gea, seco);
    // 7. fusion + heads (fwp packed B)
    fused_mfma<<<64,256,0,stream>>>(lg16, la16, seco, sec, fwp, fb, rw, rb, mw, mb, (float*)d_out);
}

// Round 14
// 282.420 us; speedup vs baseline: 1.0179x; 1.0179x over previous
//
#include <hip/hip_runtime.h>
#include <math.h>

#define LRELU_A 0.2f
#define NEGBIG (-9.0e15f)

typedef _Float16 f16;
typedef _Float16 f16x8 __attribute__((ext_vector_type(8)));
typedef _Float16 f16x4 __attribute__((ext_vector_type(4)));
typedef float floatx4 __attribute__((ext_vector_type(4)));

__device__ __forceinline__ float rcpf(float x){ return __builtin_amdgcn_rcpf(x); }
__device__ __forceinline__ float sigm(float x){ return rcpf(1.0f+__expf(-x)); }
// Fused GRU gate update, 5 trans ops (exact algebra):
// h' = (1-z)*tanh(u) + z*h = [ (En-1)*Ez + h*(En+1) ] / [ (En+1)*(1+Ez) ]
__device__ __forceinline__ float gru_fuse(float xr, float xz, float xn_pre, float ghn, float h){
    float Er = __expf(-xr);
    float r  = rcpf(1.0f + Er);
    float En = __expf(2.0f*(xn_pre + r*ghn));
    float Ez = __expf(-xz);
    float Dn = En + 1.0f;
    float num = fmaf(h, Dn, (En - 1.0f)*Ez);
    float den = Dn * (1.0f + Ez);
    return num * rcpf(den);
}
__device__ __forceinline__ f16x8 load_cvt8(const float* __restrict__ p){
    float4 a = *(const float4*)p; float4 b = *(const float4*)(p+4);
    f16x8 r; r[0]=(f16)a.x; r[1]=(f16)a.y; r[2]=(f16)a.z; r[3]=(f16)a.w;
    r[4]=(f16)b.x; r[5]=(f16)b.y; r[6]=(f16)b.z; r[7]=(f16)b.w;
    return r;
}
#define MFMA16(A,B,C) __builtin_amdgcn_mfma_f32_16x16x32_f16((A),(B),(C),0,0,0)

// ---------------------------------------------------------------------------
// prep: Wcat1 | WcatA | WTp | fwp | gep | ggp | bucketing (+pos inverse).
// WTp/fwp/gep/ggp are FRAGMENT-MAJOR packed B matrices: addr =
// (frag*64 + lane)*8 + e -> one contiguous 1KB wave read per B-fragment.
// ---------------------------------------------------------------------------
__global__ __launch_bounds__(256) void prep_kernel(
    const float* __restrict__ g1Wih, const float* __restrict__ g1Whh,
    const float* __restrict__ gaWih, const float* __restrict__ gaWhh,
    const float* __restrict__ giW,   const float* __restrict__ fw,
    const float* __restrict__ geW,   const float* __restrict__ ggWih,
    const int* __restrict__ sec,
    f16* __restrict__ Wcat1, f16* __restrict__ WcatA,
    f16* __restrict__ WTp, f16* __restrict__ fwp, f16* __restrict__ gep,
    f16* __restrict__ ggp,
    int* __restrict__ memflat, int* __restrict__ pos,
    int* __restrict__ cnt, int* __restrict__ base)
{
    __shared__ int cs[16], wsc[16];
    const int b = blockIdx.x, tid = threadIdx.x;
    if (b < 160){                      // Wcat1: INF=16, INFPAD=32, KTOT=160
        for (int idx = b*256+tid; idx < 512*160; idx += 160*256){
            int r = idx/160, k = idx - r*160;
            float v = 0.0f;
            if (r < 256){ if (k < 32){ if (k < 16) v = g1Wih[r*16+k]; } else v = g1Whh[r*128 + (k-32)]; }
            else if (r < 384){ if (k < 16) v = g1Wih[r*16+k]; }
            else { if (k >= 32) v = g1Whh[(r-128)*128 + (k-32)]; }
            Wcat1[idx] = (f16)v;
        }
    } else if (b < 416){               // WcatA: INF=128, INFPAD=128, KTOT=256
        for (int idx = (b-160)*256+tid; idx < 512*256; idx += 256*256){
            int r = idx >> 8, k = idx & 255;
            float v = 0.0f;
            if (r < 256){ v = (k < 128) ? gaWih[r*128+k] : gaWhh[r*128 + (k-128)]; }
            else if (r < 384){ if (k < 128) v = gaWih[r*128+k]; }
            else { if (k >= 128) v = gaWhh[(r-128)*128 + (k-128)]; }
            WcatA[idx] = (f16)v;
        }
    } else if (b < 480){               // WTp: giW packed, frag=(jb*4+kb), 16384
        int idx = (b-416)*256+tid;
        int e=idx&7, lane=(idx>>3)&63, fr=idx>>9;
        int kb=fr&3, jb=fr>>2;
        int k = kb*32 + (lane>>4)*8 + e, col = jb*16 + (lane&15);
        WTp[idx] = (f16)giW[k*128 + col];
    } else if (b < 672){               // fwp: fw packed, frag=(jb*12+kb), 49152
        int idx = (b-480)*256+tid;
        int e=idx&7, lane=(idx>>3)&63, fr=idx>>9;
        int kb=fr%12, jb=fr/12;
        int k = kb*32 + (lane>>4)*8 + e, col = jb*16 + (lane&15);
        fwp[idx] = (f16)fw[k*128 + col];
    } else if (b < 736){               // gep: geW packed, frag=(jb*4+kb), 16384
        int idx = (b-672)*256+tid;
        int e=idx&7, lane=(idx>>3)&63, fr=idx>>9;
        int kb=fr&3, jb=fr>>2;
        int k = kb*32 + (lane>>4)*8 + e, col = jb*16 + (lane&15);
        gep[idx] = (f16)geW[k*128 + col];
    } else if (b < 928){               // ggp: ggWih packed, frag=((G*8+jb)*4+kb), 49152
        int idx = (b-736)*256+tid;
        int e=idx&7, lane=(idx>>3)&63, fr=idx>>9;
        int kb=fr&3, jb=(fr>>2)&7, G=fr>>5;
        int row = G*128 + jb*16 + (lane&15), k = kb*32 + (lane>>4)*8 + e;
        ggp[idx] = (f16)ggWih[row*128 + k];
    } else {                           // bucket + inverse permutation
        if (tid < 16) cs[tid] = 0;
        __syncthreads();
        for (int s = tid; s < 2048; s += 256) atomicAdd(&cs[sec[s]], 1);
        __syncthreads();
        if (tid == 0){
            int acc = 0;
            for (int g=0; g<16; g++){ cnt[g]=cs[g]; base[g]=acc; wsc[g]=acc; acc+=cs[g]; }
        }
        __syncthreads();
        for (int s = tid; s < 2048; s += 256){
            int g = sec[s];
            int p = atomicAdd(&wsc[g], 1);
            memflat[p] = s;
            pos[s] = p;
        }
    }
}

// ---------------------------------------------------------------------------
// Short GRU+attn — R9 config (M=32, 8 waves, 512 thr, no spill, 8 tiles/blk,
// x reg-prefetch) + t=0 SPECIALIZATION: h==0 at step 0, so the 16 h-MFMAs,
// 8 hs ds_reads and the per-tile hs[1] zeroing are provably zero-contribution
// and removed (bit-exact: zero C accumulator == skipping zero-A MFMAs).
// ---------------------------------------------------------------------------
__global__ __launch_bounds__(512,2) void gru_short(
    const float* __restrict__ x, const f16* __restrict__ Wcat,
    const float* __restrict__ bih, const float* __restrict__ bhh,
    const float* __restrict__ aw, const float* __restrict__ ab,
    f16* __restrict__ out)
{
    __shared__ __align__(16) f16 xs[5][32][40];
    __shared__ __align__(16) f16 hs[2][32][136];
    __shared__ float scpart[2][8][32];
    const int tid = threadIdx.x, w = tid>>6, lane = tid&63;
    const int c = lane&15, quad = lane>>4;

    { f16x4 z4 = {0,0,0,0};
      f16x4* zx = (f16x4*)&xs[0][0][0];
      for (int i=tid; i<1600; i+=512) zx[i] = z4; }

    const int jrow = w*16 + c;
    f16x8 Ar[5], Az[5], Agi, Agh[4];
#pragma unroll
    for (int kb=0;kb<5;kb++){
        Ar[kb] = *(const f16x8*)&Wcat[(size_t)(jrow)*160 + kb*32 + quad*8];
        Az[kb] = *(const f16x8*)&Wcat[(size_t)(128+jrow)*160 + kb*32 + quad*8];
    }
    Agi = *(const f16x8*)&Wcat[(size_t)(256+jrow)*160 + quad*8];
#pragma unroll
    for (int i=0;i<4;i++)
        Agh[i] = *(const f16x8*)&Wcat[(size_t)(384+jrow)*160 + 32 + i*32 + quad*8];

    float brz_r[4], brz_z[4], b_in[4], b_hn[4], awr[4];
#pragma unroll
    for (int r=0;r<4;r++){
        int j = w*16 + quad*4 + r;
        brz_r[r] = bih[j] + bhh[j];
        brz_z[r] = bih[128+j] + bhh[128+j];
        b_in[r] = bih[256+j]; b_hn[r] = bhh[256+j];
        awr[r] = aw[j];
    }
    const float abv = ab[0];

    const int s0i = tid/20,        q0 = tid - 20*s0i;
    const int i1  = tid + 512;
    const int s1i = i1/20,         q1 = i1 - 20*s1i;
    const bool pf1 = (tid < 128);
    float4 xpf0, xpf1;
    {
        const size_t base0 = (size_t)(blockIdx.x*8)*32;
        xpf0 = *(const float4*)&x[(base0 + s0i)*80 + q0*4];
        if (pf1) xpf1 = *(const float4*)&x[(base0 + s1i)*80 + q1*4];
    }

#pragma unroll 1
    for (int tile=0; tile<8; ++tile){
        const int s0 = (blockIdx.x*8 + tile)*32;
        {
            int t = (q0*4)>>4, f = (q0*4)&15;
            f16x4 h4; h4[0]=(f16)xpf0.x; h4[1]=(f16)xpf0.y; h4[2]=(f16)xpf0.z; h4[3]=(f16)xpf0.w;
            *(f16x4*)&xs[t][s0i][f] = h4;
            if (pf1){
                int t1 = (q1*4)>>4, f1 = (q1*4)&15;
                f16x4 g4; g4[0]=(f16)xpf1.x; g4[1]=(f16)xpf1.y; g4[2]=(f16)xpf1.z; g4[3]=(f16)xpf1.w;
                *(f16x4*)&xs[t1][s1i][f1] = g4;
            }
        }
        if (tile < 7){
            const size_t basen = (size_t)(s0 + 32);
            xpf0 = *(const float4*)&x[(basen + s0i)*80 + q0*4];
            if (pf1) xpf1 = *(const float4*)&x[(basen + s1i)*80 + q1*4];
        }
        float hreg[2][4], aacc[2][4], l_[2] = {0.0f, 0.0f};
#pragma unroll
        for (int st=0; st<2; st++)
#pragma unroll
            for (int r=0;r<4;r++){ aacc[st][r]=0.0f; }
        __syncthreads();

        // ---- t = 0 specialized: h==0 -> x-MFMAs only, no hs read/zero ----
        {
            float sp[2];
#pragma unroll
            for (int st=0; st<2; st++){
                f16x8 Bx = *(const f16x8*)&xs[0][st*16+c][quad*8];
                floatx4 ar = {0,0,0,0}, az = {0,0,0,0}, agi = {0,0,0,0};
                ar = MFMA16(Ar[0], Bx, ar);
                az = MFMA16(Az[0], Bx, az);
                agi = MFMA16(Agi, Bx, agi);
                f16x4 h4;
                sp[st] = 0.0f;
#pragma unroll
                for (int r=0;r<4;r++){
                    float hn = gru_fuse(ar[r] + brz_r[r], az[r] + brz_z[r],
                                        agi[r] + b_in[r], b_hn[r], 0.0f);
                    hreg[st][r] = hn; h4[r] = (f16)hn;
                    sp[st] += hn * awr[r];
                }
                *(f16x4*)&hs[0][st*16 + c][w*16 + quad*4] = h4;
            }
#pragma unroll
            for (int st=0; st<2; st++){
                sp[st] += __shfl_xor(sp[st], 16);
                sp[st] += __shfl_xor(sp[st], 32);
            }
            if (lane < 16){ scpart[0][w][lane] = sp[0]; scpart[0][w][16+lane] = sp[1]; }
            __syncthreads();
        }

#pragma unroll 1
        for (int t=1; t<5; ++t){
            const int rp = (t&1)^1, wp = t&1;
            f16x8 Bx[2], Bh[2][4];
#pragma unroll
            for (int st=0; st<2; st++){
                Bx[st] = *(const f16x8*)&xs[t][st*16+c][quad*8];
#pragma unroll
                for (int i=0;i<4;i++)
                    Bh[st][i] = *(const f16x8*)&hs[rp][st*16+c][i*32+quad*8];
            }
            // lagged attention: apply step t-1's weight to h_{t-1}
            {
#pragma unroll
                for (int st=0; st<2; st++){
                    float sc = abv;
#pragma unroll
                    for (int ww=0; ww<8; ww++) sc += scpart[rp][ww][st*16+c];
                    float e = __expf(sc);
                    l_[st] += e;
#pragma unroll
                    for (int r=0;r<4;r++) aacc[st][r] += e*hreg[st][r];
                }
            }
            float sp[2];
#pragma unroll
            for (int st=0; st<2; st++){
                floatx4 ar = {0,0,0,0}, az = {0,0,0,0}, agi = {0,0,0,0}, agh = {0,0,0,0};
                ar = MFMA16(Ar[0], Bx[st], ar);
                az = MFMA16(Az[0], Bx[st], az);
                agi = MFMA16(Agi, Bx[st], agi);
#pragma unroll
                for (int i=0;i<4;i++){
                    ar = MFMA16(Ar[1+i], Bh[st][i], ar);
                    az = MFMA16(Az[1+i], Bh[st][i], az);
                    agh = MFMA16(Agh[i], Bh[st][i], agh);
                }
                f16x4 h4;
                sp[st] = 0.0f;
#pragma unroll
                for (int r=0;r<4;r++){
                    float hn = gru_fuse(ar[r] + brz_r[r], az[r] + brz_z[r],
                                        agi[r] + b_in[r], agh[r] + b_hn[r], hreg[st][r]);
                    hreg[st][r] = hn; h4[r] = (f16)hn;
                    sp[st] += hn * awr[r];
                }
                *(f16x4*)&hs[wp][st*16 + c][w*16 + quad*4] = h4;
            }
#pragma unroll
            for (int st=0; st<2; st++){
                sp[st] += __shfl_xor(sp[st], 16);
                sp[st] += __shfl_xor(sp[st], 32);
            }
            if (lane < 16){ scpart[wp][w][lane] = sp[0]; scpart[wp][w][16+lane] = sp[1]; }
            __syncthreads();
        }
        // drain last step (t=4 wrote scpart[0], hreg holds h_4)
#pragma unroll
        for (int st=0; st<2; st++){
            float sc = abv;
#pragma unroll
            for (int ww=0; ww<8; ww++) sc += scpart[0][ww][st*16+c];
            float e = __expf(sc);
            l_[st] += e;
            float inv = rcpf(l_[st]);
            f16x4 h4;
#pragma unroll
            for (int r=0;r<4;r++) h4[r] = (f16)((aacc[st][r] + e*hreg[st][r])*inv);
            *(f16x4*)&hs[0][st*16 + c][w*16 + quad*4] = h4;
        }
        __syncthreads();
        { int s = tid>>4, p = tid&15;
          *(f16x8*)&out[(size_t)(s0+s)*128 + p*8] = *(const f16x8*)&hs[0][s][p*8]; }
    }
}

// ---------------------------------------------------------------------------
// Merged: blocks 0..255 = la GRU+attn (T=32, M=8, R12 structure + t=0
// specialization: no hs/xs zeroing, step 0 = x-MFMAs only);
// blocks 256..319 = gat_prep (WTp fragment-packed loads).
// ---------------------------------------------------------------------------
__global__ __launch_bounds__(512,2) void gru_la_gatprep(
    const f16* __restrict__ xseq, const f16* __restrict__ Wcat,
    const float* __restrict__ bih, const float* __restrict__ bhh,
    const float* __restrict__ aw, const float* __restrict__ ab,
    f16* __restrict__ out,
    const f16* __restrict__ WTp, const float* __restrict__ gia,
    const int* __restrict__ memflat,
    f16* __restrict__ Whs, float* __restrict__ ers, float* __restrict__ el)
{
    __shared__ __align__(16) f16 xs[2][16][136];
    __shared__ __align__(16) f16 hs[2][16][136];
    __shared__ float scpart[2][8][16];
    __shared__ __align__(16) float tbuf[32][132];
    __shared__ int rows[32];
    const int tid = threadIdx.x, w = tid>>6, lane = tid&63;
    const int c = lane&15, quad = lane>>4;

    if (blockIdx.x >= 256){
        // ---------------- gat_prep (8 waves, 1 jb per wave) ----------------
        const int p0 = (blockIdx.x-256)*32;
        if (tid < 32) rows[tid] = memflat[p0 + tid];
        __syncthreads();
        f16x8 A[2][4];
#pragma unroll
        for (int mt=0;mt<2;mt++)
#pragma unroll
            for (int kb=0;kb<4;kb++)
                A[mt][kb] = *(const f16x8*)&xseq[((size_t)rows[mt*16+c]*32 + 31)*128 + kb*32 + quad*8];
        {
            f16x8 B[4];
#pragma unroll
            for (int kb=0;kb<4;kb++)
                B[kb] = *(const f16x8*)&WTp[(((size_t)(w*4+kb))*64 + lane)*8];
            floatx4 acc[2] = {{0,0,0,0},{0,0,0,0}};
#pragma unroll
            for (int kb=0;kb<4;kb++){
                acc[0] = MFMA16(A[0][kb], B[kb], acc[0]);
                acc[1] = MFMA16(A[1][kb], B[kb], acc[1]);
            }
#pragma unroll
            for (int mt=0;mt<2;mt++)
#pragma unroll
                for (int r=0;r<4;r++)
                    tbuf[mt*16 + quad*4 + r][w*16 + c] = acc[mt][r];
        }
        __syncthreads();
        for (int i=tid; i<1024; i+=512){
            int s = i>>5, p = i&31;
            float4 v = *(const float4*)&tbuf[s][p*4];
            f16x4 h4; h4[0]=(f16)v.x; h4[1]=(f16)v.y; h4[2]=(f16)v.z; h4[3]=(f16)v.w;
            *(f16x4*)&Whs[(size_t)(p0+s)*128 + p*4] = h4;
        }
        for (int k=0; k<4; k++){
            int row = w*4 + k;
            float w0 = tbuf[row][lane], w1 = tbuf[row][64+lane];
            float v1 = w0*gia[lane]     + w1*gia[64+lane];
            float v2 = w0*gia[128+lane] + w1*gia[192+lane];
#pragma unroll
            for (int off=32; off; off>>=1){ v1 += __shfl_down(v1,off); v2 += __shfl_down(v2,off); }
            if (lane==0){ el[rows[row]] = v1; ers[p0+row] = v2; }
        }
        return;
    }
    // ------------------------------ gru_la ------------------------------
    const int s0 = blockIdx.x*8;
    // stage x[0] -> buf0 (all used cols written; no zeroing needed)
    if (tid < 128){
        int s = tid>>4, p = tid&15;
        *(f16x8*)&xs[0][s][p*8] = *(const f16x8*)&xseq[((size_t)(s0+s)*32 + 0)*128 + p*8];
    }
    const int jrow = w*16 + c;
    f16x8 Ar[8], Az[8], Agi[4], Agh[4];
#pragma unroll
    for (int kb=0;kb<8;kb++){
        Ar[kb] = *(const f16x8*)&Wcat[(size_t)(jrow)*256 + kb*32 + quad*8];
        Az[kb] = *(const f16x8*)&Wcat[(size_t)(128+jrow)*256 + kb*32 + quad*8];
    }
#pragma unroll
    for (int i=0;i<4;i++){
        Agi[i] = *(const f16x8*)&Wcat[(size_t)(256+jrow)*256 + i*32 + quad*8];
        Agh[i] = *(const f16x8*)&Wcat[(size_t)(384+jrow)*256 + 128 + i*32 + quad*8];
    }
    float brz_r[4], brz_z[4], b_in[4], b_hn[4], awr[4];
#pragma unroll
    for (int r=0;r<4;r++){
        int j = w*16 + quad*4 + r;
        brz_r[r] = bih[j] + bhh[j];
        brz_z[r] = bih[128+j] + bhh[128+j];
        b_in[r] = bih[256+j]; b_hn[r] = bhh[256+j];
        awr[r] = aw[j];
    }
    const float abv = ab[0];
    float hreg[4] = {0,0,0,0}, aacc[4] = {0,0,0,0}, l_ = 0.0f;
    __syncthreads();

    // ---- t = 0 specialized: h==0 -> x-MFMAs only ----
    {
        f16x8 Bx[4];
#pragma unroll
        for (int i=0;i<4;i++) Bx[i] = *(const f16x8*)&xs[0][c][i*32+quad*8];
        f16x8 xstage;
        if (tid < 128){
            int s = tid>>4, p = tid&15;
            xstage = *(const f16x8*)&xseq[((size_t)(s0+s)*32 + 1)*128 + p*8];
        }
        floatx4 ar = {0,0,0,0}, az = {0,0,0,0}, agi = {0,0,0,0};
#pragma unroll
        for (int i=0;i<4;i++){
            ar  = MFMA16(Ar[i],  Bx[i], ar);
            az  = MFMA16(Az[i],  Bx[i], az);
            agi = MFMA16(Agi[i], Bx[i], agi);
        }
        f16x4 h4;
        float sp = 0.0f;
#pragma unroll
        for (int r=0;r<4;r++){
            float hn = gru_fuse(ar[r] + brz_r[r], az[r] + brz_z[r],
                                agi[r] + b_in[r], b_hn[r], 0.0f);
            hreg[r] = hn; h4[r] = (f16)hn;
            sp += hn * awr[r];
        }
        *(f16x4*)&hs[0][c][w*16 + quad*4] = h4;
        if (tid < 128){
            int s = tid>>4, p = tid&15;
            *(f16x8*)&xs[1][s][p*8] = xstage;
        }
        sp += __shfl_xor(sp, 16);
        sp += __shfl_xor(sp, 32);
        if (lane < 16) scpart[0][w][lane] = sp;
        __syncthreads();
    }

#pragma unroll 1
    for (int t=1; t<32; ++t){
        const int rp = (t&1)^1, wp = t&1, xp = t&1;
        f16x8 Bx[4], Bh[4];
#pragma unroll
        for (int i=0;i<4;i++){
            Bx[i] = *(const f16x8*)&xs[xp][c][i*32+quad*8];
            Bh[i] = *(const f16x8*)&hs[rp][c][i*32+quad*8];
        }
        f16x8 xstage;
        const bool do_stage = (t < 31) && (tid < 128);
        if (do_stage){
            int s = tid>>4, p = tid&15;
            xstage = *(const f16x8*)&xseq[((size_t)(s0+s)*32 + t+1)*128 + p*8];
        }
        {
            float sc = abv;
#pragma unroll
            for (int ww=0; ww<8; ww++) sc += scpart[rp][ww][c];
            float e = __expf(sc);
            l_ += e;
#pragma unroll
            for (int r=0;r<4;r++) aacc[r] += e*hreg[r];
        }
        floatx4 ar = {0,0,0,0}, az = {0,0,0,0}, agi = {0,0,0,0}, agh = {0,0,0,0};
#pragma unroll
        for (int i=0;i<4;i++){
            ar = MFMA16(Ar[i], Bx[i], ar);
            az = MFMA16(Az[i], Bx[i], az);
            agi = MFMA16(Agi[i], Bx[i], agi);
        }
#pragma unroll
        for (int i=0;i<4;i++){
            ar = MFMA16(Ar[4+i], Bh[i], ar);
            az = MFMA16(Az[4+i], Bh[i], az);
            agh = MFMA16(Agh[i], Bh[i], agh);
        }
        f16x4 h4;
        float sp = 0.0f;
#pragma unroll
        for (int r=0;r<4;r++){
            float hn = gru_fuse(ar[r] + brz_r[r], az[r] + brz_z[r],
                                agi[r] + b_in[r], agh[r] + b_hn[r], hreg[r]);
            hreg[r] = hn; h4[r] = (f16)hn;
            sp += hn * awr[r];
        }
        *(f16x4*)&hs[wp][c][w*16 + quad*4] = h4;
        if (do_stage){
            int s = tid>>4, p = tid&15;
            *(f16x8*)&xs[xp^1][s][p*8] = xstage;
        }
        sp += __shfl_xor(sp, 16);
        sp += __shfl_xor(sp, 32);
        if (lane < 16) scpart[wp][w][lane] = sp;
        __syncthreads();
    }
    // drain (t=31 wrote scpart[1])
    {
        float sc = abv;
#pragma unroll
        for (int ww=0; ww<8; ww++) sc += scpart[1][ww][c];
        float e = __expf(sc);
        l_ += e;
        float inv = rcpf(l_);
        f16x4 h4;
#pragma unroll
        for (int r=0;r<4;r++) h4[r] = (f16)((aacc[r] + e*hreg[r])*inv);
        *(f16x4*)&hs[1][c][w*16 + quad*4] = h4;
    }
    __syncthreads();
    if (tid < 128){
        int s = tid>>4, p = tid&15;
        *(f16x8*)&out[(size_t)(s0+s)*128 + p*8] = *(const f16x8*)&hs[1][s][p*8];
    }
}

// ---------------------------------------------------------------------------
// GAT intra, member-list. One wave per row; streams sorted f16 Wh.
// ---------------------------------------------------------------------------
__global__ __launch_bounds__(256) void gat_intra_mem_kernel(
    const f16* __restrict__ Whs, const float* __restrict__ ers,
    const float* __restrict__ el, const int* __restrict__ sec,
    const int* __restrict__ cnt, const int* __restrict__ base,
    f16* __restrict__ outp, int S)
{
    int wave = threadIdx.x>>6, lane = threadIdx.x&63;
    int i = blockIdx.x*4 + wave;
    if (i>=S) return;
    int g = sec[i];
    int n = cnt[g], b = base[g];
    float eli = el[i];
    float m = -INFINITY;
    for (int jj=lane; jj<n; jj+=64){
        float v = eli + ers[b+jj]; v = v>0.f? v : LRELU_A*v;
        m = fmaxf(m, v);
    }
#pragma unroll
    for (int off=32; off; off>>=1) m = fmaxf(m, __shfl_xor(m, off));
    float l = 0.f, c0=0.f, c1=0.f;
#pragma unroll 4
    for (int jj=0; jj<n; jj++){
        float v = eli + ers[b+jj]; v = v>0.f? v : LRELU_A*v;
        float p = __expf(v-m);
        l += p;
        c0 += p*(float)Whs[(size_t)(b+jj)*128 + lane];
        c1 += p*(float)Whs[(size_t)(b+jj)*128 + 64 + lane];
    }
    float il = rcpf(l);
    c0 *= il; c1 *= il;
    outp[(size_t)i*128+lane]    = (f16)(c0>0.f? c0 : expm1f(c0));
    outp[(size_t)i*128+64+lane] = (f16)(c1>0.f? c1 : expm1f(c1));
}

// ---------------------------------------------------------------------------
// lg: T=1 GRU via MFMA; B from ggp (fragment-packed f16).
// Writes orig-order lg16 and sorted lgs.
// ---------------------------------------------------------------------------
__global__ __launch_bounds__(256) void lg_mfma(
    const f16* __restrict__ intra16, const f16* __restrict__ ggp,
    const float* __restrict__ bih, const float* __restrict__ bhh,
    const int* __restrict__ pos,
    f16* __restrict__ lgout, f16* __restrict__ lgs)
{
    __shared__ __align__(16) f16 tbuf[32][136];
    const int tid = threadIdx.x, w = tid>>6, lane = tid&63;
    const int c = lane&15, quad = lane>>4;
    const int s0 = blockIdx.x*32;
    f16x8 A[2][4];
#pragma unroll
    for (int mt=0;mt<2;mt++)
#pragma unroll
        for (int kb=0;kb<4;kb++)
            A[mt][kb] = *(const f16x8*)&intra16[(size_t)(s0+mt*16+c)*128 + kb*32 + quad*8];
#pragma unroll
    for (int i=0;i<2;i++){
        int jb = w*2 + i;
        int j = jb*16 + c;
        f16x8 Br[4], Bz[4], Bn[4];
#pragma unroll
        for (int kb=0;kb<4;kb++){
            Br[kb] = *(const f16x8*)&ggp[(((size_t)((0*8+jb)*4+kb))*64 + lane)*8];
            Bz[kb] = *(const f16x8*)&ggp[(((size_t)((1*8+jb)*4+kb))*64 + lane)*8];
            Bn[kb] = *(const f16x8*)&ggp[(((size_t)((2*8+jb)*4+kb))*64 + lane)*8];
        }
        float b_r = bih[j] + bhh[j];
        float b_z = bih[128+j] + bhh[128+j];
        float b_i = bih[256+j], b_h = bhh[256+j];
        floatx4 ar[2] = {{0,0,0,0},{0,0,0,0}};
        floatx4 az[2] = {{0,0,0,0},{0,0,0,0}};
        floatx4 an[2] = {{0,0,0,0},{0,0,0,0}};
#pragma unroll
        for (int kb=0;kb<4;kb++)
#pragma unroll
            for (int mt=0;mt<2;mt++){
                ar[mt] = MFMA16(A[mt][kb], Br[kb], ar[mt]);
                az[mt] = MFMA16(A[mt][kb], Bz[kb], az[mt]);
                an[mt] = MFMA16(A[mt][kb], Bn[kb], an[mt]);
            }
#pragma unroll
        for (int mt=0;mt<2;mt++)
#pragma unroll
            for (int r=0;r<4;r++){
                float Er = __expf(-(ar[mt][r] + b_r));
                float rg = rcpf(1.0f + Er);
                float En = __expf(2.0f*(an[mt][r] + b_i + rg*b_h));
                float Ez = __expf(-(az[mt][r] + b_z));
                float v = (En - 1.0f)*Ez * rcpf((En + 1.0f)*(1.0f + Ez));
                tbuf[mt*16 + quad*4 + r][j] = (f16)v;
            }
    }
    __syncthreads();
    for (int i=tid; i<512; i+=256){
        int s = i>>4, p = i&15;
        f16x8 v = *(const f16x8*)&tbuf[s][p*8];
        *(f16x8*)&lgout[(size_t)(s0+s)*128 + p*8] = v;
        *(f16x8*)&lgs[(size_t)pos[s0+s]*128 + p*8] = v;
    }
}

// ---------------------------------------------------------------------------
// Fused tail: sector means (sorted lgs, contiguous) + inter GAT.
// Phase B via MFMA with gep (fragment-packed).
// ---------------------------------------------------------------------------
__global__ __launch_bounds__(1024) void gat_inter_fused(
    const f16* __restrict__ lgs, const int* __restrict__ cnt,
    const int* __restrict__ base, const int* __restrict__ adj,
    const f16* __restrict__ gep, const float* __restrict__ a,
    float* __restrict__ outp)
{
    __shared__ __align__(16) float hs[16][132];
    __shared__ __align__(16) float Whs[16][132];
    __shared__ float el[16], er[16];
    __shared__ float att[16][16];
    const int tid = threadIdx.x, w = tid>>6, lane = tid&63;
    const int c = lane&15, quad = lane>>4;

    // Phase A: wave w sums sector w over its contiguous sorted rows.
    {
        int n = cnt[w], b = base[w];
        const int rowoff = lane>>4;
        const int colb = (lane&15)*8;
        float acc[8] = {0,0,0,0,0,0,0,0};
        for (int r = rowoff; r < n; r += 4){
            f16x8 v = *(const f16x8*)&lgs[(size_t)(b+r)*128 + colb];
#pragma unroll
            for (int k=0;k<8;k++) acc[k] += (float)v[k];
        }
#pragma unroll
        for (int k=0;k<8;k++){
            acc[k] += __shfl_xor(acc[k], 16);
            acc[k] += __shfl_xor(acc[k], 32);
        }
        if (lane < 16){
            float inv = rcpf(fmaxf((float)n, 1.0f));
#pragma unroll
            for (int k=0;k<8;k++) hs[w][colb+k] = acc[k]*inv;
        }
    }
    __syncthreads();
    // Phase B (MFMA): Whs = hs @ geW; wave w<8 computes column tile w.
    if (w < 8){
        f16x8 A[4], B[4];
#pragma unroll
        for (int kb=0;kb<4;kb++){
            A[kb] = load_cvt8(&hs[c][kb*32 + quad*8]);
            B[kb] = *(const f16x8*)&gep[(((size_t)(w*4+kb))*64 + lane)*8];
        }
        floatx4 acc = {0,0,0,0};
#pragma unroll
        for (int kb=0;kb<4;kb++) acc = MFMA16(A[kb], B[kb], acc);
#pragma unroll
        for (int r=0;r<4;r++) Whs[quad*4 + r][w*16 + c] = acc[r];
    }
    __syncthreads();
    // Phase C: el/er — wave w reduces sector w; lanes 0-31: el, 32-63: er.
    {
        int half = lane>>5, l = lane&31;
        const float* av = a + half*128;
        float acc2 = 0.f;
#pragma unroll
        for (int k=0;k<4;k++) acc2 += Whs[w][l+32*k]*av[l+32*k];
#pragma unroll
        for (int off=1; off<32; off<<=1) acc2 += __shfl_xor(acc2, off);
        if (l==0){ if (half) er[w]=acc2; else el[w]=acc2; }
    }
    __syncthreads();
    // Phase D: 16x16 masked softmax
    if (tid<16){
        int i=tid; float m=NEGBIG; float e[16];
        for(int j=0;j<16;j++){
            float v = el[i]+er[j]; v = v>0.f? v : LRELU_A*v;
            e[j] = (adj[i*16+j]>0)? v : NEGBIG;
            m = fmaxf(m,e[j]);
        }
        float l=0.f;
        for(int j=0;j<16;j++){ float p=__expf(e[j]-m); att[i][j]=p; l+=p; }
        float il = rcpf(l);
        for(int j=0;j<16;j++) att[i][j] *= il;
    }
    __syncthreads();
    // Phase E: att @ Whs + ELU
#pragma unroll
    for (int i=0;i<2;i++){
        int idx=i*1024+tid; int o=idx&127, s=idx>>7;
        float acc=0.f;
#pragma unroll
        for(int j=0;j<16;j++) acc += att[s][j]*Whs[j][o];
        outp[s*128+o] = acc>0.f? acc : expm1f(acc);
    }
}

// ---------------------------------------------------------------------------
// fused = [lg|la|sec_ps] @ fw + fb, then both heads. B from fwp (packed).
// ---------------------------------------------------------------------------
__global__ __launch_bounds__(256) void fused_mfma(
    const f16* __restrict__ lg16, const f16* __restrict__ la16,
    const float* __restrict__ seco, const int* __restrict__ sec,
    const f16* __restrict__ fwp,
    const float* __restrict__ fb, const float* __restrict__ rw,
    const float* __restrict__ rb, const float* __restrict__ mw,
    const float* __restrict__ mb, float* __restrict__ outp)
{
    __shared__ float rpart[4][32], mpart[4][32];
    const int tid = threadIdx.x, w = tid>>6, lane = tid&63;
    const int c = lane&15, quad = lane>>4;
    const int s0 = blockIdx.x*32;
    f16x8 A[2][12];
#pragma unroll
    for (int mt=0;mt<2;mt++){
        int row = s0 + mt*16 + c;
        int g = sec[row];
#pragma unroll
        for (int kb=0;kb<4;kb++){
            A[mt][kb]   = *(const f16x8*)&lg16[(size_t)row*128 + kb*32 + quad*8];
            A[mt][4+kb] = *(const f16x8*)&la16[(size_t)row*128 + kb*32 + quad*8];
            A[mt][8+kb] = load_cvt8(&seco[(size_t)g*128 + kb*32 + quad*8]);
        }
    }
    float rsum[2][4] = {{0,0,0,0},{0,0,0,0}};
    float msum[2][4] = {{0,0,0,0},{0,0,0,0}};
#pragma unroll
    for (int i=0;i<2;i++){
        int jb = w*2 + i;
        int col = jb*16 + c;
        f16x8 B[12];
#pragma unroll
        for (int kb=0;kb<12;kb++)
            B[kb] = *(const f16x8*)&fwp[(((size_t)(jb*12+kb))*64 + lane)*8];
        floatx4 acc[2] = {{0,0,0,0},{0,0,0,0}};
#pragma unroll
        for (int kb=0;kb<12;kb++){
            acc[0] = MFMA16(A[0][kb], B[kb], acc[0]);
            acc[1] = MFMA16(A[1][kb], B[kb], acc[1]);
        }
        float fbv = fb[col], rwv = rw[col], mwv = mw[col];
#pragma unroll
        for (int mt=0;mt<2;mt++)
#pragma unroll
            for (int r=0;r<4;r++){
                float fu = acc[mt][r] + fbv;
                rsum[mt][r] += fu*rwv;
                msum[mt][r] += fu*mwv;
            }
    }
#pragma unroll
    for (int mt=0;mt<2;mt++)
#pragma unroll
        for (int r=0;r<4;r++){
#pragma unroll
            for (int off=1; off<16; off<<=1){
                rsum[mt][r] += __shfl_xor(rsum[mt][r], off);
                msum[mt][r] += __shfl_xor(msum[mt][r], off);
            }
            if (c==0){
                rpart[w][mt*16 + quad*4 + r] = rsum[mt][r];
                mpart[w][mt*16 + quad*4 + r] = msum[mt][r];
            }
        }
    __syncthreads();
    if (tid < 32){
        int s = tid;
        float rs = rb[0], ms = mb[0];
#pragma unroll
        for (int ww=0; ww<4; ww++){ rs += rpart[ww][s]; ms += mpart[ww][s]; }
        outp[s0+s] = rs;
        outp[2048 + s0 + s] = sigm(ms);
    }
}

extern "C" void kernel_launch(void* const* d_in, const int* in_sizes, int n_in,
                              void* d_out, int out_size, void* d_ws, size_t ws_size,
                              hipStream_t stream) {
    const float* sf    = (const float*)d_in[0];
    const int*   sec   = (const int*)  d_in[1];
    const int*   adj   = (const int*)  d_in[2];
    const float* g1Wih = (const float*)d_in[3];
    const float* g1Whh = (const float*)d_in[4];
    const float* g1bih = (const float*)d_in[5];
    const float* g1bhh = (const float*)d_in[6];
    const float* a1w   = (const float*)d_in[7];
    const float* a1b   = (const float*)d_in[8];
    const float* giW   = (const float*)d_in[9];
    const float* gia   = (const float*)d_in[10];
    const float* ggWih = (const float*)d_in[11];
    const float* ggbih = (const float*)d_in[13];
    const float* ggbhh = (const float*)d_in[14];
    const float* gaWih = (const float*)d_in[17];
    const float* gaWhh = (const float*)d_in[18];
    const float* gabih = (const float*)d_in[19];
    const float* gabhh = (const float*)d_in[20];
    const float* aaw   = (const float*)d_in[21];
    const float* aab   = (const float*)d_in[22];
    const float* geW   = (const float*)d_in[23];
    const float* gea   = (const float*)d_in[24];
    const float* fw    = (const float*)d_in[25];
    const float* fb    = (const float*)d_in[26];
    const float* rw    = (const float*)d_in[27];
    const float* rb    = (const float*)d_in[28];
    const float* mw    = (const float*)d_in[29];
    const float* mb    = (const float*)d_in[30];

    char* p = (char*)d_ws;
    f16*   shrt16 = (f16*)p;   p += (size_t)65536*128*2;
    f16*   intra16= (f16*)p;   p += (size_t)262144*2;
    f16*   lg16   = (f16*)p;   p += (size_t)262144*2;
    f16*   la16   = (f16*)p;   p += (size_t)262144*2;
    f16*   Whs    = (f16*)p;   p += (size_t)262144*2;
    f16*   lgs    = (f16*)p;   p += (size_t)262144*2;
    f16*   Wcat1  = (f16*)p;   p += (size_t)512*160*2;
    f16*   WcatA  = (f16*)p;   p += (size_t)512*256*2;
    f16*   WTp    = (f16*)p;   p += (size_t)16384*2;
    f16*   gep    = (f16*)p;   p += (size_t)16384*2;
    f16*   fwp    = (f16*)p;   p += (size_t)49152*2;
    f16*   ggp    = (f16*)p;   p += (size_t)49152*2;
    float* el     = (float*)p; p += 2048*4;
    float* ers    = (float*)p; p += 2048*4;
    float* seco   = (float*)p; p += 2048*4;
    int*   memflat= (int*)p;   p += 2048*4;
    int*   pos    = (int*)p;   p += 2048*4;
    int*   cnt    = (int*)p;   p += 16*4;
    int*   basep  = (int*)p;   p += 16*4;

    // 0. all weight prep (fragment-packed B matrices) + bucketing
    prep_kernel<<<929,256,0,stream>>>(g1Wih, g1Whh, gaWih, gaWhh, giW, fw, geW, ggWih, sec,
                                      Wcat1, WcatA, WTp, fwp, gep, ggp,
                                      memflat, pos, cnt, basep);
    // 1. short GRU+attn — R9 config + t=0 specialization
    gru_short<<<256,512,0,stream>>>(sf, Wcat1, g1bih, g1bhh, a1w, a1b, shrt16);
    // 2. la GRU+attn (t=0 specialized) || gat_prep — merged
    gru_la_gatprep<<<320,512,0,stream>>>(shrt16, WcatA, gabih, gabhh, aaw, aab, la16,
                                         WTp, gia, memflat, Whs, ers, el);
    // 3. intra-sector GAT
    gat_intra_mem_kernel<<<512,256,0,stream>>>(Whs, ers, el, sec, cnt, basep, intra16, 2048);
    // 4. lg (T=1 simplification) — ggp packed B; also emits sorted lgs
    lg_mfma<<<64,256,0,stream>>>(intra16, ggp, ggbih, ggbhh, pos, lg16, lgs);
    // 5+6. fused sector means + inter-sector GAT (phase B via MFMA + gep)
    gat_inter_fused<<<1,1024,0,stream>>>(lgs, cnt, basep, adj, gep, gea, seco);
    // 7. fusion + heads (fwp packed B)
    fused_mfma<<<64,256,0,stream>>>(lg16, la16, seco, sec, fwp, fb, rw, rb, mw, mb, (float*)d_out);
}

// Round 15
// 278.433 us; speedup vs baseline: 1.0324x; 1.0143x over previous
//
#include <hip/hip_runtime.h>
#include <math.h>

#define LRELU_A 0.2f
#define NEGBIG (-9.0e15f)

typedef _Float16 f16;
typedef _Float16 f16x8 __attribute__((ext_vector_type(8)));
typedef _Float16 f16x4 __attribute__((ext_vector_type(4)));
typedef float floatx4 __attribute__((ext_vector_type(4)));

__device__ __forceinline__ float rcpf(float x){ return __builtin_amdgcn_rcpf(x); }
__device__ __forceinline__ float sigm(float x){ return rcpf(1.0f+__expf(-x)); }
// Fused GRU gate update, 5 trans ops (exact algebra):
// h' = (1-z)*tanh(u) + z*h = [ (En-1)*Ez + h*(En+1) ] / [ (En+1)*(1+Ez) ]
__device__ __forceinline__ float gru_fuse(float xr, float xz, float xn_pre, float ghn, float h){
    float Er = __expf(-xr);
    float r  = rcpf(1.0f + Er);
    float En = __expf(2.0f*(xn_pre + r*ghn));
    float Ez = __expf(-xz);
    float Dn = En + 1.0f;
    float num = fmaf(h, Dn, (En - 1.0f)*Ez);
    float den = Dn * (1.0f + Ez);
    return num * rcpf(den);
}
__device__ __forceinline__ f16x8 load_cvt8(const float* __restrict__ p){
    float4 a = *(const float4*)p; float4 b = *(const float4*)(p+4);
    f16x8 r; r[0]=(f16)a.x; r[1]=(f16)a.y; r[2]=(f16)a.z; r[3]=(f16)a.w;
    r[4]=(f16)b.x; r[5]=(f16)b.y; r[6]=(f16)b.z; r[7]=(f16)b.w;
    return r;
}
#define MFMA16(A,B,C) __builtin_amdgcn_mfma_f32_16x16x32_f16((A),(B),(C),0,0,0)

// ---------------------------------------------------------------------------
// prep1: ONLY Wcat1 — the sole dependency of gru_short. The rest of the old
// prep kernel (WcatA/WTp/fwp/gep/ggp/bucketing) is folded into the gru_short
// launch as extra blocks, so it executes CONCURRENTLY with gru_short (R15:
// streams serialize kernels; one-launch merge is the only way to overlap).
// ---------------------------------------------------------------------------
__global__ __launch_bounds__(256) void prep1_kernel(
    const float* __restrict__ g1Wih, const float* __restrict__ g1Whh,
    f16* __restrict__ Wcat1)
{
    const int b = blockIdx.x, tid = threadIdx.x;
    for (int idx = b*256+tid; idx < 512*160; idx += 160*256){
        int r = idx/160, k = idx - r*160;
        float v = 0.0f;
        if (r < 256){ if (k < 32){ if (k < 16) v = g1Wih[r*16+k]; } else v = g1Whh[r*128 + (k-32)]; }
        else if (r < 384){ if (k < 16) v = g1Wih[r*16+k]; }
        else { if (k >= 32) v = g1Whh[(r-128)*128 + (k-32)]; }
        Wcat1[idx] = (f16)v;
    }
}

// ---------------------------------------------------------------------------
// Short GRU+attn — R14 config (M=32, 8 waves, 8 tiles/blk, x reg-prefetch,
// t=0 specialization) + two R15 changes:
//  (1) blocks 256..768 run the rest of weight prep concurrently (prep2):
//      WcatA | WTp | fwp | gep | ggp | bucketing, re-indexed for 512 thr.
//  (2) tile epilogue writes h4 directly to global (2x8B/thread) — removes
//      the per-tile LDS roundtrip + one barrier (L2 write-combines lines).
// ---------------------------------------------------------------------------
__global__ __launch_bounds__(512,2) void gru_short(
    const float* __restrict__ x, const f16* __restrict__ Wcat,
    const float* __restrict__ bih, const float* __restrict__ bhh,
    const float* __restrict__ aw, const float* __restrict__ ab,
    f16* __restrict__ out,
    // prep2 inputs/outputs:
    const float* __restrict__ gaWih, const float* __restrict__ gaWhh,
    const float* __restrict__ giW,   const float* __restrict__ fw,
    const float* __restrict__ geW,   const float* __restrict__ ggWih,
    const int* __restrict__ sec,
    f16* __restrict__ WcatA, f16* __restrict__ WTp, f16* __restrict__ fwp,
    f16* __restrict__ gep,   f16* __restrict__ ggp,
    int* __restrict__ memflat, int* __restrict__ pos,
    int* __restrict__ cnt, int* __restrict__ base)
{
    __shared__ __align__(16) f16 xs[5][32][40];
    __shared__ __align__(16) f16 hs[2][32][136];
    __shared__ float scpart[2][8][32];
    __shared__ int cs[16], wsc[16];
    const int tid = threadIdx.x, w = tid>>6, lane = tid&63;
    const int c = lane&15, quad = lane>>4;

    if (blockIdx.x >= 256){
        // ------------------------- prep2 branch -------------------------
        const int b2 = blockIdx.x - 256;
        if (b2 < 256){                 // WcatA: 131072 elems
            int idx = b2*512 + tid;
            int r = idx >> 8, k = idx & 255;
            float v = 0.0f;
            if (r < 256){ v = (k < 128) ? gaWih[r*128+k] : gaWhh[r*128 + (k-128)]; }
            else if (r < 384){ if (k < 128) v = gaWih[r*128+k]; }
            else { if (k >= 128) v = gaWhh[(r-128)*128 + (k-128)]; }
            WcatA[idx] = (f16)v;
        } else if (b2 < 288){          // WTp: 16384
            int idx = (b2-256)*512 + tid;
            int e=idx&7, ln=(idx>>3)&63, fr=idx>>9;
            int kb=fr&3, jb=fr>>2;
            int k = kb*32 + (ln>>4)*8 + e, col = jb*16 + (ln&15);
            WTp[idx] = (f16)giW[k*128 + col];
        } else if (b2 < 384){          // fwp: 49152
            int idx = (b2-288)*512 + tid;
            int e=idx&7, ln=(idx>>3)&63, fr=idx>>9;
            int kb=fr%12, jb=fr/12;
            int k = kb*32 + (ln>>4)*8 + e, col = jb*16 + (ln&15);
            fwp[idx] = (f16)fw[k*128 + col];
        } else if (b2 < 416){          // gep: 16384
            int idx = (b2-384)*512 + tid;
            int e=idx&7, ln=(idx>>3)&63, fr=idx>>9;
            int kb=fr&3, jb=fr>>2;
            int k = kb*32 + (ln>>4)*8 + e, col = jb*16 + (ln&15);
            gep[idx] = (f16)geW[k*128 + col];
        } else if (b2 < 512){          // ggp: 49152
            int idx = (b2-416)*512 + tid;
            int e=idx&7, ln=(idx>>3)&63, fr=idx>>9;
            int kb=fr&3, jb=(fr>>2)&7, G=fr>>5;
            int row = G*128 + jb*16 + (ln&15), k = kb*32 + (ln>>4)*8 + e;
            ggp[idx] = (f16)ggWih[row*128 + k];
        } else {                       // bucketing + inverse permutation
            if (tid < 16) cs[tid] = 0;
            __syncthreads();
            for (int s = tid; s < 2048; s += 512) atomicAdd(&cs[sec[s]], 1);
            __syncthreads();
            if (tid == 0){
                int acc = 0;
                for (int g=0; g<16; g++){ cnt[g]=cs[g]; base[g]=acc; wsc[g]=acc; acc+=cs[g]; }
            }
            __syncthreads();
            for (int s = tid; s < 2048; s += 512){
                int g = sec[s];
                int p2 = atomicAdd(&wsc[g], 1);
                memflat[p2] = s;
                pos[s] = p2;
            }
        }
        return;
    }
    // ------------------------- gru_short branch -------------------------
    { f16x4 z4 = {0,0,0,0};
      f16x4* zx = (f16x4*)&xs[0][0][0];
      for (int i=tid; i<1600; i+=512) zx[i] = z4; }

    const int jrow = w*16 + c;
    f16x8 Ar[5], Az[5], Agi, Agh[4];
#pragma unroll
    for (int kb=0;kb<5;kb++){
        Ar[kb] = *(const f16x8*)&Wcat[(size_t)(jrow)*160 + kb*32 + quad*8];
        Az[kb] = *(const f16x8*)&Wcat[(size_t)(128+jrow)*160 + kb*32 + quad*8];
    }
    Agi = *(const f16x8*)&Wcat[(size_t)(256+jrow)*160 + quad*8];
#pragma unroll
    for (int i=0;i<4;i++)
        Agh[i] = *(const f16x8*)&Wcat[(size_t)(384+jrow)*160 + 32 + i*32 + quad*8];

    float brz_r[4], brz_z[4], b_in[4], b_hn[4], awr[4];
#pragma unroll
    for (int r=0;r<4;r++){
        int j = w*16 + quad*4 + r;
        brz_r[r] = bih[j] + bhh[j];
        brz_z[r] = bih[128+j] + bhh[128+j];
        b_in[r] = bih[256+j]; b_hn[r] = bhh[256+j];
        awr[r] = aw[j];
    }
    const float abv = ab[0];

    const int s0i = tid/20,        q0 = tid - 20*s0i;
    const int i1  = tid + 512;
    const int s1i = i1/20,         q1 = i1 - 20*s1i;
    const bool pf1 = (tid < 128);
    float4 xpf0, xpf1;
    {
        const size_t base0 = (size_t)(blockIdx.x*8)*32;
        xpf0 = *(const float4*)&x[(base0 + s0i)*80 + q0*4];
        if (pf1) xpf1 = *(const float4*)&x[(base0 + s1i)*80 + q1*4];
    }

#pragma unroll 1
    for (int tile=0; tile<8; ++tile){
        const int s0 = (blockIdx.x*8 + tile)*32;
        {
            int t = (q0*4)>>4, f = (q0*4)&15;
            f16x4 h4; h4[0]=(f16)xpf0.x; h4[1]=(f16)xpf0.y; h4[2]=(f16)xpf0.z; h4[3]=(f16)xpf0.w;
            *(f16x4*)&xs[t][s0i][f] = h4;
            if (pf1){
                int t1 = (q1*4)>>4, f1 = (q1*4)&15;
                f16x4 g4; g4[0]=(f16)xpf1.x; g4[1]=(f16)xpf1.y; g4[2]=(f16)xpf1.z; g4[3]=(f16)xpf1.w;
                *(f16x4*)&xs[t1][s1i][f1] = g4;
            }
        }
        if (tile < 7){
            const size_t basen = (size_t)(s0 + 32);
            xpf0 = *(const float4*)&x[(basen + s0i)*80 + q0*4];
            if (pf1) xpf1 = *(const float4*)&x[(basen + s1i)*80 + q1*4];
        }
        float hreg[2][4], aacc[2][4], l_[2] = {0.0f, 0.0f};
#pragma unroll
        for (int st=0; st<2; st++)
#pragma unroll
            for (int r=0;r<4;r++){ aacc[st][r]=0.0f; }
        __syncthreads();

        // ---- t = 0 specialized: h==0 -> x-MFMAs only, no hs read/zero ----
        {
            float sp[2];
#pragma unroll
            for (int st=0; st<2; st++){
                f16x8 Bx = *(const f16x8*)&xs[0][st*16+c][quad*8];
                floatx4 ar = {0,0,0,0}, az = {0,0,0,0}, agi = {0,0,0,0};
                ar = MFMA16(Ar[0], Bx, ar);
                az = MFMA16(Az[0], Bx, az);
                agi = MFMA16(Agi, Bx, agi);
                f16x4 h4;
                sp[st] = 0.0f;
#pragma unroll
                for (int r=0;r<4;r++){
                    float hn = gru_fuse(ar[r] + brz_r[r], az[r] + brz_z[r],
                                        agi[r] + b_in[r], b_hn[r], 0.0f);
                    hreg[st][r] = hn; h4[r] = (f16)hn;
                    sp[st] += hn * awr[r];
                }
                *(f16x4*)&hs[0][st*16 + c][w*16 + quad*4] = h4;
            }
#pragma unroll
            for (int st=0; st<2; st++){
                sp[st] += __shfl_xor(sp[st], 16);
                sp[st] += __shfl_xor(sp[st], 32);
            }
            if (lane < 16){ scpart[0][w][lane] = sp[0]; scpart[0][w][16+lane] = sp[1]; }
            __syncthreads();
        }

#pragma unroll 1
        for (int t=1; t<5; ++t){
            const int rp = (t&1)^1, wp = t&1;
            f16x8 Bx[2], Bh[2][4];
#pragma unroll
            for (int st=0; st<2; st++){
                Bx[st] = *(const f16x8*)&xs[t][st*16+c][quad*8];
#pragma unroll
                for (int i=0;i<4;i++)
                    Bh[st][i] = *(const f16x8*)&hs[rp][st*16+c][i*32+quad*8];
            }
            // lagged attention: apply step t-1's weight to h_{t-1}
            {
#pragma unroll
                for (int st=0; st<2; st++){
                    float sc = abv;
#pragma unroll
                    for (int ww=0; ww<8; ww++) sc += scpart[rp][ww][st*16+c];
                    float e = __expf(sc);
                    l_[st] += e;
#pragma unroll
                    for (int r=0;r<4;r++) aacc[st][r] += e*hreg[st][r];
                }
            }
            float sp[2];
#pragma unroll
            for (int st=0; st<2; st++){
                floatx4 ar = {0,0,0,0}, az = {0,0,0,0}, agi = {0,0,0,0}, agh = {0,0,0,0};
                ar = MFMA16(Ar[0], Bx[st], ar);
                az = MFMA16(Az[0], Bx[st], az);
                agi = MFMA16(Agi, Bx[st], agi);
#pragma unroll
                for (int i=0;i<4;i++){
                    ar = MFMA16(Ar[1+i], Bh[st][i], ar);
                    az = MFMA16(Az[1+i], Bh[st][i], az);
                    agh = MFMA16(Agh[i], Bh[st][i], agh);
                }
                f16x4 h4;
                sp[st] = 0.0f;
#pragma unroll
                for (int r=0;r<4;r++){
                    float hn = gru_fuse(ar[r] + brz_r[r], az[r] + brz_z[r],
                                        agi[r] + b_in[r], agh[r] + b_hn[r], hreg[st][r]);
                    hreg[st][r] = hn; h4[r] = (f16)hn;
                    sp[st] += hn * awr[r];
                }
                *(f16x4*)&hs[wp][st*16 + c][w*16 + quad*4] = h4;
            }
#pragma unroll
            for (int st=0; st<2; st++){
                sp[st] += __shfl_xor(sp[st], 16);
                sp[st] += __shfl_xor(sp[st], 32);
            }
            if (lane < 16){ scpart[wp][w][lane] = sp[0]; scpart[wp][w][16+lane] = sp[1]; }
            __syncthreads();
        }
        // drain (t=4 wrote scpart[0], hreg holds h_4) — DIRECT global store:
        // each thread owns rows st*16+c, cols w*16+quad*4..+3 (8B x2).
        // No LDS roundtrip, no extra barrier (xs/scpart/hs races separated
        // by the t=4 and tile-start barriers — audited R15).
#pragma unroll
        for (int st=0; st<2; st++){
            float sc = abv;
#pragma unroll
            for (int ww=0; ww<8; ww++) sc += scpart[0][ww][st*16+c];
            float e = __expf(sc);
            l_[st] += e;
            float inv = rcpf(l_[st]);
            f16x4 h4;
#pragma unroll
            for (int r=0;r<4;r++) h4[r] = (f16)((aacc[st][r] + e*hreg[st][r])*inv);
            *(f16x4*)&out[(size_t)(s0 + st*16 + c)*128 + w*16 + quad*4] = h4;
        }
    }
}

// ---------------------------------------------------------------------------
// Merged: blocks 0..255 = la GRU+attn (T=32, M=8, t=0 specialized);
// blocks 256..319 = gat_prep (WTp fragment-packed loads).
// ---------------------------------------------------------------------------
__global__ __launch_bounds__(512,2) void gru_la_gatprep(
    const f16* __restrict__ xseq, const f16* __restrict__ Wcat,
    const float* __restrict__ bih, const float* __restrict__ bhh,
    const float* __restrict__ aw, const float* __restrict__ ab,
    f16* __restrict__ out,
    const f16* __restrict__ WTp, const float* __restrict__ gia,
    const int* __restrict__ memflat,
    f16* __restrict__ Whs, float* __restrict__ ers, float* __restrict__ el)
{
    __shared__ __align__(16) f16 xs[2][16][136];
    __shared__ __align__(16) f16 hs[2][16][136];
    __shared__ float scpart[2][8][16];
    __shared__ __align__(16) float tbuf[32][132];
    __shared__ int rows[32];
    const int tid = threadIdx.x, w = tid>>6, lane = tid&63;
    const int c = lane&15, quad = lane>>4;

    if (blockIdx.x >= 256){
        // ---------------- gat_prep (8 waves, 1 jb per wave) ----------------
        const int p0 = (blockIdx.x-256)*32;
        if (tid < 32) rows[tid] = memflat[p0 + tid];
        __syncthreads();
        f16x8 A[2][4];
#pragma unroll
        for (int mt=0;mt<2;mt++)
#pragma unroll
            for (int kb=0;kb<4;kb++)
                A[mt][kb] = *(const f16x8*)&xseq[((size_t)rows[mt*16+c]*32 + 31)*128 + kb*32 + quad*8];
        {
            f16x8 B[4];
#pragma unroll
            for (int kb=0;kb<4;kb++)
                B[kb] = *(const f16x8*)&WTp[(((size_t)(w*4+kb))*64 + lane)*8];
            floatx4 acc[2] = {{0,0,0,0},{0,0,0,0}};
#pragma unroll
            for (int kb=0;kb<4;kb++){
                acc[0] = MFMA16(A[0][kb], B[kb], acc[0]);
                acc[1] = MFMA16(A[1][kb], B[kb], acc[1]);
            }
#pragma unroll
            for (int mt=0;mt<2;mt++)
#pragma unroll
                for (int r=0;r<4;r++)
                    tbuf[mt*16 + quad*4 + r][w*16 + c] = acc[mt][r];
        }
        __syncthreads();
        for (int i=tid; i<1024; i+=512){
            int s = i>>5, p = i&31;
            float4 v = *(const float4*)&tbuf[s][p*4];
            f16x4 h4; h4[0]=(f16)v.x; h4[1]=(f16)v.y; h4[2]=(f16)v.z; h4[3]=(f16)v.w;
            *(f16x4*)&Whs[(size_t)(p0+s)*128 + p*4] = h4;
        }
        for (int k=0; k<4; k++){
            int row = w*4 + k;
            float w0 = tbuf[row][lane], w1 = tbuf[row][64+lane];
            float v1 = w0*gia[lane]     + w1*gia[64+lane];
            float v2 = w0*gia[128+lane] + w1*gia[192+lane];
#pragma unroll
            for (int off=32; off; off>>=1){ v1 += __shfl_down(v1,off); v2 += __shfl_down(v2,off); }
            if (lane==0){ el[rows[row]] = v1; ers[p0+row] = v2; }
        }
        return;
    }
    // ------------------------------ gru_la ------------------------------
    const int s0 = blockIdx.x*8;
    if (tid < 128){
        int s = tid>>4, p = tid&15;
        *(f16x8*)&xs[0][s][p*8] = *(const f16x8*)&xseq[((size_t)(s0+s)*32 + 0)*128 + p*8];
    }
    const int jrow = w*16 + c;
    f16x8 Ar[8], Az[8], Agi[4], Agh[4];
#pragma unroll
    for (int kb=0;kb<8;kb++){
        Ar[kb] = *(const f16x8*)&Wcat[(size_t)(jrow)*256 + kb*32 + quad*8];
        Az[kb] = *(const f16x8*)&Wcat[(size_t)(128+jrow)*256 + kb*32 + quad*8];
    }
#pragma unroll
    for (int i=0;i<4;i++){
        Agi[i] = *(const f16x8*)&Wcat[(size_t)(256+jrow)*256 + i*32 + quad*8];
        Agh[i] = *(const f16x8*)&Wcat[(size_t)(384+jrow)*256 + 128 + i*32 + quad*8];
    }
    float brz_r[4], brz_z[4], b_in[4], b_hn[4], awr[4];
#pragma unroll
    for (int r=0;r<4;r++){
        int j = w*16 + quad*4 + r;
        brz_r[r] = bih[j] + bhh[j];
        brz_z[r] = bih[128+j] + bhh[128+j];
        b_in[r] = bih[256+j]; b_hn[r] = bhh[256+j];
        awr[r] = aw[j];
    }
    const float abv = ab[0];
    float hreg[4] = {0,0,0,0}, aacc[4] = {0,0,0,0}, l_ = 0.0f;
    __syncthreads();

    // ---- t = 0 specialized: h==0 -> x-MFMAs only ----
    {
        f16x8 Bx[4];
#pragma unroll
        for (int i=0;i<4;i++) Bx[i] = *(const f16x8*)&xs[0][c][i*32+quad*8];
        f16x8 xstage;
        if (tid < 128){
            int s = tid>>4, p = tid&15;
            xstage = *(const f16x8*)&xseq[((size_t)(s0+s)*32 + 1)*128 + p*8];
        }
        floatx4 ar = {0,0,0,0}, az = {0,0,0,0}, agi = {0,0,0,0};
#pragma unroll
        for (int i=0;i<4;i++){
            ar  = MFMA16(Ar[i],  Bx[i], ar);
            az  = MFMA16(Az[i],  Bx[i], az);
            agi = MFMA16(Agi[i], Bx[i], agi);
        }
        f16x4 h4;
        float sp = 0.0f;
#pragma unroll
        for (int r=0;r<4;r++){
            float hn = gru_fuse(ar[r] + brz_r[r], az[r] + brz_z[r],
                                agi[r] + b_in[r], b_hn[r], 0.0f);
            hreg[r] = hn; h4[r] = (f16)hn;
            sp += hn * awr[r];
        }
        *(f16x4*)&hs[0][c][w*16 + quad*4] = h4;
        if (tid < 128){
            int s = tid>>4, p = tid&15;
            *(f16x8*)&xs[1][s][p*8] = xstage;
        }
        sp += __shfl_xor(sp, 16);
        sp += __shfl_xor(sp, 32);
        if (lane < 16) scpart[0][w][lane] = sp;
        __syncthreads();
    }

#pragma unroll 1
    for (int t=1; t<32; ++t){
        const int rp = (t&1)^1, wp = t&1, xp = t&1;
        f16x8 Bx[4], Bh[4];
#pragma unroll
        for (int i=0;i<4;i++){
            Bx[i] = *(const f16x8*)&xs[xp][c][i*32+quad*8];
            Bh[i] = *(const f16x8*)&hs[rp][c][i*32+quad*8];
        }
        f16x8 xstage;
        const bool do_stage = (t < 31) && (tid < 128);
        if (do_stage){
            int s = tid>>4, p = tid&15;
            xstage = *(const f16x8*)&xseq[((size_t)(s0+s)*32 + t+1)*128 + p*8];
        }
        {
            float sc = abv;
#pragma unroll
            for (int ww=0; ww<8; ww++) sc += scpart[rp][ww][c];
            float e = __expf(sc);
            l_ += e;
#pragma unroll
            for (int r=0;r<4;r++) aacc[r] += e*hreg[r];
        }
        floatx4 ar = {0,0,0,0}, az = {0,0,0,0}, agi = {0,0,0,0}, agh = {0,0,0,0};
#pragma unroll
        for (int i=0;i<4;i++){
            ar = MFMA16(Ar[i], Bx[i], ar);
            az = MFMA16(Az[i], Bx[i], az);
            agi = MFMA16(Agi[i], Bx[i], agi);
        }
#pragma unroll
        for (int i=0;i<4;i++){
            ar = MFMA16(Ar[4+i], Bh[i], ar);
            az = MFMA16(Az[4+i], Bh[i], az);
            agh = MFMA16(Agh[i], Bh[i], agh);
        }
        f16x4 h4;
        float sp = 0.0f;
#pragma unroll
        for (int r=0;r<4;r++){
            float hn = gru_fuse(ar[r] + brz_r[r], az[r] + brz_z[r],
                                agi[r] + b_in[r], agh[r] + b_hn[r], hreg[r]);
            hreg[r] = hn; h4[r] = (f16)hn;
            sp += hn * awr[r];
        }
        *(f16x4*)&hs[wp][c][w*16 + quad*4] = h4;
        if (do_stage){
            int s = tid>>4, p = tid&15;
            *(f16x8*)&xs[xp^1][s][p*8] = xstage;
        }
        sp += __shfl_xor(sp, 16);
        sp += __shfl_xor(sp, 32);
        if (lane < 16) scpart[wp][w][lane] = sp;
        __syncthreads();
    }
    // drain (t=31 wrote scpart[1])
    {
        float sc = abv;
#pragma unroll
        for (int ww=0; ww<8; ww++) sc += scpart[1][ww][c];
        float e = __expf(sc);
        l_ += e;
        float inv = rcpf(l_);
        f16x4 h4;
#pragma unroll
        for (int r=0;r<4;r++) h4[r] = (f16)((aacc[r] + e*hreg[r])*inv);
        if (c < 8)
            *(f16x4*)&out[(size_t)(s0 + c)*128 + w*16 + quad*4] = h4;
    }
}

// ---------------------------------------------------------------------------
// GAT intra, member-list. One wave per row; streams sorted f16 Wh.
// ---------------------------------------------------------------------------
__global__ __launch_bounds__(256) void gat_intra_mem_kernel(
    const f16* __restrict__ Whs, const float* __restrict__ ers,
    const float* __restrict__ el, const int* __restrict__ sec,
    const int* __restrict__ cnt, const int* __restrict__ base,
    f16* __restrict__ outp, int S)
{
    int wave = threadIdx.x>>6, lane = threadIdx.x&63;
    int i = blockIdx.x*4 + wave;
    if (i>=S) return;
    int g = sec[i];
    int n = cnt[g], b = base[g];
    float eli = el[i];
    float m = -INFINITY;
    for (int jj=lane; jj<n; jj+=64){
        float v = eli + ers[b+jj]; v = v>0.f? v : LRELU_A*v;
        m = fmaxf(m, v);
    }
#pragma unroll
    for (int off=32; off; off>>=1) m = fmaxf(m, __shfl_xor(m, off));
    float l = 0.f, c0=0.f, c1=0.f;
#pragma unroll 4
    for (int jj=0; jj<n; jj++){
        float v = eli + ers[b+jj]; v = v>0.f? v : LRELU_A*v;
        float p = __expf(v-m);
        l += p;
        c0 += p*(float)Whs[(size_t)(b+jj)*128 + lane];
        c1 += p*(float)Whs[(size_t)(b+jj)*128 + 64 + lane];
    }
    float il = rcpf(l);
    c0 *= il; c1 *= il;
    outp[(size_t)i*128+lane]    = (f16)(c0>0.f? c0 : expm1f(c0));
    outp[(size_t)i*128+64+lane] = (f16)(c1>0.f? c1 : expm1f(c1));
}

// ---------------------------------------------------------------------------
// lg: T=1 GRU via MFMA; B from ggp (fragment-packed f16).
// Writes orig-order lg16 and sorted lgs.
// ---------------------------------------------------------------------------
__global__ __launch_bounds__(256) void lg_mfma(
    const f16* __restrict__ intra16, const f16* __restrict__ ggp,
    const float* __restrict__ bih, const float* __restrict__ bhh,
    const int* __restrict__ pos,
    f16* __restrict__ lgout, f16* __restrict__ lgs)
{
    __shared__ __align__(16) f16 tbuf[32][136];
    const int tid = threadIdx.x, w = tid>>6, lane = tid&63;
    const int c = lane&15, quad = lane>>4;
    const int s0 = blockIdx.x*32;
    f16x8 A[2][4];
#pragma unroll
    for (int mt=0;mt<2;mt++)
#pragma unroll
        for (int kb=0;kb<4;kb++)
            A[mt][kb] = *(const f16x8*)&intra16[(size_t)(s0+mt*16+c)*128 + kb*32 + quad*8];
#pragma unroll
    for (int i=0;i<2;i++){
        int jb = w*2 + i;
        int j = jb*16 + c;
        f16x8 Br[4], Bz[4], Bn[4];
#pragma unroll
        for (int kb=0;kb<4;kb++){
            Br[kb] = *(const f16x8*)&ggp[(((size_t)((0*8+jb)*4+kb))*64 + lane)*8];
            Bz[kb] = *(const f16x8*)&ggp[(((size_t)((1*8+jb)*4+kb))*64 + lane)*8];
            Bn[kb] = *(const f16x8*)&ggp[(((size_t)((2*8+jb)*4+kb))*64 + lane)*8];
        }
        float b_r = bih[j] + bhh[j];
        float b_z = bih[128+j] + bhh[128+j];
        float b_i = bih[256+j], b_h = bhh[256+j];
        floatx4 ar[2] = {{0,0,0,0},{0,0,0,0}};
        floatx4 az[2] = {{0,0,0,0},{0,0,0,0}};
        floatx4 an[2] = {{0,0,0,0},{0,0,0,0}};
#pragma unroll
        for (int kb=0;kb<4;kb++)
#pragma unroll
            for (int mt=0;mt<2;mt++){
                ar[mt] = MFMA16(A[mt][kb], Br[kb], ar[mt]);
                az[mt] = MFMA16(A[mt][kb], Bz[kb], az[mt]);
                an[mt] = MFMA16(A[mt][kb], Bn[kb], an[mt]);
            }
#pragma unroll
        for (int mt=0;mt<2;mt++)
#pragma unroll
            for (int r=0;r<4;r++){
                float Er = __expf(-(ar[mt][r] + b_r));
                float rg = rcpf(1.0f + Er);
                float En = __expf(2.0f*(an[mt][r] + b_i + rg*b_h));
                float Ez = __expf(-(az[mt][r] + b_z));
                float v = (En - 1.0f)*Ez * rcpf((En + 1.0f)*(1.0f + Ez));
                tbuf[mt*16 + quad*4 + r][j] = (f16)v;
            }
    }
    __syncthreads();
    for (int i=tid; i<512; i+=256){
        int s = i>>4, p = i&15;
        f16x8 v = *(const f16x8*)&tbuf[s][p*8];
        *(f16x8*)&lgout[(size_t)(s0+s)*128 + p*8] = v;
        *(f16x8*)&lgs[(size_t)pos[s0+s]*128 + p*8] = v;
    }
}

// ---------------------------------------------------------------------------
// Fused tail: sector means (sorted lgs, contiguous) + inter GAT.
// Phase B via MFMA with gep (fragment-packed).
// ---------------------------------------------------------------------------
__global__ __launch_bounds__(1024) void gat_inter_fused(
    const f16* __restrict__ lgs, const int* __restrict__ cnt,
    const int* __restrict__ base, const int* __restrict__ adj,
    const f16* __restrict__ gep, const float* __restrict__ a,
    float* __restrict__ outp)
{
    __shared__ __align__(16) float hs[16][132];
    __shared__ __align__(16) float Whs[16][132];
    __shared__ float el[16], er[16];
    __shared__ float att[16][16];
    const int tid = threadIdx.x, w = tid>>6, lane = tid&63;
    const int c = lane&15, quad = lane>>4;

    // Phase A: wave w sums sector w over its contiguous sorted rows.
    {
        int n = cnt[w], b = base[w];
        const int rowoff = lane>>4;
        const int colb = (lane&15)*8;
        float acc[8] = {0,0,0,0,0,0,0,0};
        for (int r = rowoff; r < n; r += 4){
            f16x8 v = *(const f16x8*)&lgs[(size_t)(b+r)*128 + colb];
#pragma unroll
            for (int k=0;k<8;k++) acc[k] += (float)v[k];
        }
#pragma unroll
        for (int k=0;k<8;k++){
            acc[k] += __shfl_xor(acc[k], 16);
            acc[k] += __shfl_xor(acc[k], 32);
        }
        if (lane < 16){
            float inv = rcpf(fmaxf((float)n, 1.0f));
#pragma unroll
            for (int k=0;k<8;k++) hs[w][colb+k] = acc[k]*inv;
        }
    }
    __syncthreads();
    // Phase B (MFMA): Whs = hs @ geW; wave w<8 computes column tile w.
    if (w < 8){
        f16x8 A[4], B[4];
#pragma unroll
        for (int kb=0;kb<4;kb++){
            A[kb] = load_cvt8(&hs[c][kb*32 + quad*8]);
            B[kb] = *(const f16x8*)&gep[(((size_t)(w*4+kb))*64 + lane)*8];
        }
        floatx4 acc = {0,0,0,0};
#pragma unroll
        for (int kb=0;kb<4;kb++) acc = MFMA16(A[kb], B[kb], acc);
#pragma unroll
        for (int r=0;r<4;r++) Whs[quad*4 + r][w*16 + c] = acc[r];
    }
    __syncthreads();
    // Phase C: el/er — wave w reduces sector w; lanes 0-31: el, 32-63: er.
    {
        int half = lane>>5, l = lane&31;
        const float* av = a + half*128;
        float acc2 = 0.f;
#pragma unroll
        for (int k=0;k<4;k++) acc2 += Whs[w][l+32*k]*av[l+32*k];
#pragma unroll
        for (int off=1; off<32; off<<=1) acc2 += __shfl_xor(acc2, off);
        if (l==0){ if (half) er[w]=acc2; else el[w]=acc2; }
    }
    __syncthreads();
    // Phase D: 16x16 masked softmax
    if (tid<16){
        int i=tid; float m=NEGBIG; float e[16];
        for(int j=0;j<16;j++){
            float v = el[i]+er[j]; v = v>0.f? v : LRELU_A*v;
            e[j] = (adj[i*16+j]>0)? v : NEGBIG;
            m = fmaxf(m,e[j]);
        }
        float l=0.f;
        for(int j=0;j<16;j++){ float p=__expf(e[j]-m); att[i][j]=p; l+=p; }
        float il = rcpf(l);
        for(int j=0;j<16;j++) att[i][j] *= il;
    }
    __syncthreads();
    // Phase E: att @ Whs + ELU
#pragma unroll
    for (int i=0;i<2;i++){
        int idx=i*1024+tid; int o=idx&127, s=idx>>7;
        float acc=0.f;
#pragma unroll
        for(int j=0;j<16;j++) acc += att[s][j]*Whs[j][o];
        outp[s*128+o] = acc>0.f? acc : expm1f(acc);
    }
}

// ---------------------------------------------------------------------------
// fused = [lg|la|sec_ps] @ fw + fb, then both heads. B from fwp (packed).
// ---------------------------------------------------------------------------
__global__ __launch_bounds__(256) void fused_mfma(
    const f16* __restrict__ lg16, const f16* __restrict__ la16,
    const float* __restrict__ seco, const int* __restrict__ sec,
    const f16* __restrict__ fwp,
    const float* __restrict__ fb, const float* __restrict__ rw,
    const float* __restrict__ rb, const float* __restrict__ mw,
    const float* __restrict__ mb, float* __restrict__ outp)
{
    __shared__ float rpart[4][32], mpart[4][32];
    const int tid = threadIdx.x, w = tid>>6, lane = tid&63;
    const int c = lane&15, quad = lane>>4;
    const int s0 = blockIdx.x*32;
    f16x8 A[2][12];
#pragma unroll
    for (int mt=0;mt<2;mt++){
        int row = s0 + mt*16 + c;
        int g = sec[row];
#pragma unroll
        for (int kb=0;kb<4;kb++){
            A[mt][kb]   = *(const f16x8*)&lg16[(size_t)row*128 + kb*32 + quad*8];
            A[mt][4+kb] = *(const f16x8*)&la16[(size_t)row*128 + kb*32 + quad*8];
            A[mt][8+kb] = load_cvt8(&seco[(size_t)g*128 + kb*32 + quad*8]);
        }
    }
    float rsum[2][4] = {{0,0,0,0},{0,0,0,0}};
    float msum[2][4] = {{0,0,0,0},{0,0,0,0}};
#pragma unroll
    for (int i=0;i<2;i++){
        int jb = w*2 + i;
        int col = jb*16 + c;
        f16x8 B[12];
#pragma unroll
        for (int kb=0;kb<12;kb++)
            B[kb] = *(const f16x8*)&fwp[(((size_t)(jb*12+kb))*64 + lane)*8];
        floatx4 acc[2] = {{0,0,0,0},{0,0,0,0}};
#pragma unroll
        for (int kb=0;kb<12;kb++){
            acc[0] = MFMA16(A[0][kb], B[kb], acc[0]);
            acc[1] = MFMA16(A[1][kb], B[kb], acc[1]);
        }
        float fbv = fb[col], rwv = rw[col], mwv = mw[col];
#pragma unroll
        for (int mt=0;mt<2;mt++)
#pragma unroll
            for (int r=0;r<4;r++){
                float fu = acc[mt][r] + fbv;
                rsum[mt][r] += fu*rwv;
                msum[mt][r] += fu*mwv;
            }
    }
#pragma unroll
    for (int mt=0;mt<2;mt++)
#pragma unroll
        for (int r=0;r<4;r++){
#pragma unroll
            for (int off=1; off<16; off<<=1){
                rsum[mt][r] += __shfl_xor(rsum[mt][r], off);
                msum[mt][r] += __shfl_xor(msum[mt][r], off);
            }
            if (c==0){
                rpart[w][mt*16 + quad*4 + r] = rsum[mt][r];
                mpart[w][mt*16 + quad*4 + r] = msum[mt][r];
            }
        }
    __syncthreads();
    if (tid < 32){
        int s = tid;
        float rs = rb[0], ms = mb[0];
#pragma unroll
        for (int ww=0; ww<4; ww++){ rs += rpart[ww][s]; ms += mpart[ww][s]; }
        outp[s0+s] = rs;
        outp[2048 + s0 + s] = sigm(ms);
    }
}

extern "C" void kernel_launch(void* const* d_in, const int* in_sizes, int n_in,
                              void* d_out, int out_size, void* d_ws, size_t ws_size,
                              hipStream_t stream) {
    const float* sf    = (const float*)d_in[0];
    const int*   sec   = (const int*)  d_in[1];
    const int*   adj   = (const int*)  d_in[2];
    const float* g1Wih = (const float*)d_in[3];
    const float* g1Whh = (const float*)d_in[4];
    const float* g1bih = (const float*)d_in[5];
    const float* g1bhh = (const float*)d_in[6];
    const float* a1w   = (const float*)d_in[7];
    const float* a1b   = (const float*)d_in[8];
    const float* giW   = (const float*)d_in[9];
    const float* gia   = (const float*)d_in[10];
    const float* ggWih = (const float*)d_in[11];
    const float* ggbih = (const float*)d_in[13];
    const float* ggbhh = (const float*)d_in[14];
    const float* gaWih = (const float*)d_in[17];
    const float* gaWhh = (const float*)d_in[18];
    const float* gabih = (const float*)d_in[19];
    const float* gabhh = (const float*)d_in[20];
    const float* aaw   = (const float*)d_in[21];
    const float* aab   = (const float*)d_in[22];
    const float* geW   = (const float*)d_in[23];
    const float* gea   = (const float*)d_in[24];
    const float* fw    = (const float*)d_in[25];
    const float* fb    = (const float*)d_in[26];
    const float* rw    = (const float*)d_in[27];
    const float* rb    = (const float*)d_in[28];
    const float* mw    = (const float*)d_in[29];
    const float* mb    = (const float*)d_in[30];

    char* p = (char*)d_ws;
    f16*   shrt16 = (f16*)p;   p += (size_t)65536*128*2;
    f16*   intra16= (f16*)p;   p += (size_t)262144*2;
    f16*   lg16   = (f16*)p;   p += (size_t)262144*2;
    f16*   la16   = (f16*)p;   p += (size_t)262144*2;
    f16*   Whs    = (f16*)p;   p += (size_t)262144*2;
    f16*   lgs    = (f16*)p;   p += (size_t)262144*2;
    f16*   Wcat1  = (f16*)p;   p += (size_t)512*160*2;
    f16*   WcatA  = (f16*)p;   p += (size_t)512*256*2;
    f16*   WTp    = (f16*)p;   p += (size_t)16384*2;
    f16*   gep    = (f16*)p;   p += (size_t)16384*2;
    f16*   fwp    = (f16*)p;   p += (size_t)49152*2;
    f16*   ggp    = (f16*)p;   p += (size_t)49152*2;
    float* el     = (float*)p; p += 2048*4;
    float* ers    = (float*)p; p += 2048*4;
    float* seco   = (float*)p; p += 2048*4;
    int*   memflat= (int*)p;   p += 2048*4;
    int*   pos    = (int*)p;   p += 2048*4;
    int*   cnt    = (int*)p;   p += 16*4;
    int*   basep  = (int*)p;   p += 16*4;

    // 0. prep1: only Wcat1 (gru_short's sole dependency)
    prep1_kernel<<<160,256,0,stream>>>(g1Wih, g1Whh, Wcat1);
    // 1. short GRU+attn (blocks 0..255) || prep2 (blocks 256..768: WcatA/WTp/
    //    fwp/gep/ggp/bucketing) — concurrent inside one launch
    gru_short<<<769,512,0,stream>>>(sf, Wcat1, g1bih, g1bhh, a1w, a1b, shrt16,
                                    gaWih, gaWhh, giW, fw, geW, ggWih, sec,
                                    WcatA, WTp, fwp, gep, ggp,
                                    memflat, pos, cnt, basep);
    // 2. la GRU+attn (t=0 specialized) || gat_prep — merged
    gru_la_gatprep<<<320,512,0,stream>>>(shrt16, WcatA, gabih, gabhh, aaw, aab, la16,
                                         WTp, gia, memflat, Whs, ers, el);
    // 3. intra-sector GAT
    gat_intra_mem_kernel<<<512,256,0,stream>>>(Whs, ers, el, sec, cnt, basep, intra16, 2048);
    // 4. lg (T=1 simplification) — ggp packed B; also emits sorted lgs
    lg_mfma<<<64,256,0,stream>>>(intra16, ggp, ggbih, ggbhh, pos, lg16, lgs);
    // 5+6. fused sector means + inter-sector GAT (phase B via MFMA + gep)
    gat_inter_fused<<<1,1024,0,stream>>>(lgs, cnt, basep, adj, gep, gea, seco);
    // 7. fusion + heads (fwp packed B)
    fused_mfma<<<64,256,0,stream>>>(lg16, la16, seco, sec, fwp, fb, rw, rb, mw, mb, (float*)d_out);
}

// Round 16
// 275.846 us; speedup vs baseline: 1.0421x; 1.0094x over previous
//
#include <hip/hip_runtime.h>
#include <math.h>

#define LRELU_A 0.2f
#define NEGBIG (-9.0e15f)

typedef _Float16 f16;
typedef _Float16 f16x8 __attribute__((ext_vector_type(8)));
typedef _Float16 f16x4 __attribute__((ext_vector_type(4)));
typedef _Float16 f16x2 __attribute__((ext_vector_type(2)));
typedef float floatx4 __attribute__((ext_vector_type(4)));

__device__ __forceinline__ float rcpf(float x){ return __builtin_amdgcn_rcpf(x); }
__device__ __forceinline__ float sigm(float x){ return rcpf(1.0f+__expf(-x)); }
// Fused GRU gate update, 5 trans ops (exact algebra):
// h' = (1-z)*tanh(u) + z*h = [ (En-1)*Ez + h*(En+1) ] / [ (En+1)*(1+Ez) ]
__device__ __forceinline__ float gru_fuse(float xr, float xz, float xn_pre, float ghn, float h){
    float Er = __expf(-xr);
    float r  = rcpf(1.0f + Er);
    float En = __expf(2.0f*(xn_pre + r*ghn));
    float Ez = __expf(-xz);
    float Dn = En + 1.0f;
    float num = fmaf(h, Dn, (En - 1.0f)*Ez);
    float den = Dn * (1.0f + Ez);
    return num * rcpf(den);
}
__device__ __forceinline__ f16x8 load_cvt8(const float* __restrict__ p){
    float4 a = *(const float4*)p; float4 b = *(const float4*)(p+4);
    f16x8 r; r[0]=(f16)a.x; r[1]=(f16)a.y; r[2]=(f16)a.z; r[3]=(f16)a.w;
    r[4]=(f16)b.x; r[5]=(f16)b.y; r[6]=(f16)b.z; r[7]=(f16)b.w;
    return r;
}
#define MFMA16(A,B,C) __builtin_amdgcn_mfma_f32_16x16x32_f16((A),(B),(C),0,0,0)

// ---------------------------------------------------------------------------
// prep1: ONLY Wcat1 — the sole dependency of gru_short. The rest of prep is
// folded into the gru_short launch (blocks 256..768) for concurrency.
// ---------------------------------------------------------------------------
__global__ __launch_bounds__(256) void prep1_kernel(
    const float* __restrict__ g1Wih, const float* __restrict__ g1Whh,
    f16* __restrict__ Wcat1)
{
    const int b = blockIdx.x, tid = threadIdx.x;
    for (int idx = b*256+tid; idx < 512*160; idx += 160*256){
        int r = idx/160, k = idx - r*160;
        float v = 0.0f;
        if (r < 256){ if (k < 32){ if (k < 16) v = g1Wih[r*16+k]; } else v = g1Whh[r*128 + (k-32)]; }
        else if (r < 384){ if (k < 16) v = g1Wih[r*16+k]; }
        else { if (k >= 32) v = g1Whh[(r-128)*128 + (k-32)]; }
        Wcat1[idx] = (f16)v;
    }
}

// ---------------------------------------------------------------------------
// Short GRU+attn — R15 config: M=32, 8 waves, 8 tiles/blk, x reg-prefetch,
// t=0 specialization, direct-store epilogue; blocks 256..768 = prep2.
// ---------------------------------------------------------------------------
__global__ __launch_bounds__(512,2) void gru_short(
    const float* __restrict__ x, const f16* __restrict__ Wcat,
    const float* __restrict__ bih, const float* __restrict__ bhh,
    const float* __restrict__ aw, const float* __restrict__ ab,
    f16* __restrict__ out,
    const float* __restrict__ gaWih, const float* __restrict__ gaWhh,
    const float* __restrict__ giW,   const float* __restrict__ fw,
    const float* __restrict__ geW,   const float* __restrict__ ggWih,
    const int* __restrict__ sec,
    f16* __restrict__ WcatA, f16* __restrict__ WTp, f16* __restrict__ fwp,
    f16* __restrict__ gep,   f16* __restrict__ ggp,
    int* __restrict__ memflat, int* __restrict__ pos,
    int* __restrict__ cnt, int* __restrict__ base)
{
    __shared__ __align__(16) f16 xs[5][32][40];
    __shared__ __align__(16) f16 hs[2][32][136];
    __shared__ float scpart[2][8][32];
    __shared__ int cs[16], wsc[16];
    const int tid = threadIdx.x, w = tid>>6, lane = tid&63;
    const int c = lane&15, quad = lane>>4;

    if (blockIdx.x >= 256){
        // ------------------------- prep2 branch -------------------------
        const int b2 = blockIdx.x - 256;
        if (b2 < 256){                 // WcatA: 131072 elems
            int idx = b2*512 + tid;
            int r = idx >> 8, k = idx & 255;
            float v = 0.0f;
            if (r < 256){ v = (k < 128) ? gaWih[r*128+k] : gaWhh[r*128 + (k-128)]; }
            else if (r < 384){ if (k < 128) v = gaWih[r*128+k]; }
            else { if (k >= 128) v = gaWhh[(r-128)*128 + (k-128)]; }
            WcatA[idx] = (f16)v;
        } else if (b2 < 288){          // WTp: 16384
            int idx = (b2-256)*512 + tid;
            int e=idx&7, ln=(idx>>3)&63, fr=idx>>9;
            int kb=fr&3, jb=fr>>2;
            int k = kb*32 + (ln>>4)*8 + e, col = jb*16 + (ln&15);
            WTp[idx] = (f16)giW[k*128 + col];
        } else if (b2 < 384){          // fwp: 49152
            int idx = (b2-288)*512 + tid;
            int e=idx&7, ln=(idx>>3)&63, fr=idx>>9;
            int kb=fr%12, jb=fr/12;
            int k = kb*32 + (ln>>4)*8 + e, col = jb*16 + (ln&15);
            fwp[idx] = (f16)fw[k*128 + col];
        } else if (b2 < 416){          // gep: 16384
            int idx = (b2-384)*512 + tid;
            int e=idx&7, ln=(idx>>3)&63, fr=idx>>9;
            int kb=fr&3, jb=fr>>2;
            int k = kb*32 + (ln>>4)*8 + e, col = jb*16 + (ln&15);
            gep[idx] = (f16)geW[k*128 + col];
        } else if (b2 < 512){          // ggp: 49152
            int idx = (b2-416)*512 + tid;
            int e=idx&7, ln=(idx>>3)&63, fr=idx>>9;
            int kb=fr&3, jb=(fr>>2)&7, G=fr>>5;
            int row = G*128 + jb*16 + (ln&15), k = kb*32 + (ln>>4)*8 + e;
            ggp[idx] = (f16)ggWih[row*128 + k];
        } else {                       // bucketing + inverse permutation
            if (tid < 16) cs[tid] = 0;
            __syncthreads();
            for (int s = tid; s < 2048; s += 512) atomicAdd(&cs[sec[s]], 1);
            __syncthreads();
            if (tid == 0){
                int acc = 0;
                for (int g=0; g<16; g++){ cnt[g]=cs[g]; base[g]=acc; wsc[g]=acc; acc+=cs[g]; }
            }
            __syncthreads();
            for (int s = tid; s < 2048; s += 512){
                int g = sec[s];
                int p2 = atomicAdd(&wsc[g], 1);
                memflat[p2] = s;
                pos[s] = p2;
            }
        }
        return;
    }
    // ------------------------- gru_short branch -------------------------
    { f16x4 z4 = {0,0,0,0};
      f16x4* zx = (f16x4*)&xs[0][0][0];
      for (int i=tid; i<1600; i+=512) zx[i] = z4; }

    const int jrow = w*16 + c;
    f16x8 Ar[5], Az[5], Agi, Agh[4];
#pragma unroll
    for (int kb=0;kb<5;kb++){
        Ar[kb] = *(const f16x8*)&Wcat[(size_t)(jrow)*160 + kb*32 + quad*8];
        Az[kb] = *(const f16x8*)&Wcat[(size_t)(128+jrow)*160 + kb*32 + quad*8];
    }
    Agi = *(const f16x8*)&Wcat[(size_t)(256+jrow)*160 + quad*8];
#pragma unroll
    for (int i=0;i<4;i++)
        Agh[i] = *(const f16x8*)&Wcat[(size_t)(384+jrow)*160 + 32 + i*32 + quad*8];

    float brz_r[4], brz_z[4], b_in[4], b_hn[4], awr[4];
#pragma unroll
    for (int r=0;r<4;r++){
        int j = w*16 + quad*4 + r;
        brz_r[r] = bih[j] + bhh[j];
        brz_z[r] = bih[128+j] + bhh[128+j];
        b_in[r] = bih[256+j]; b_hn[r] = bhh[256+j];
        awr[r] = aw[j];
    }
    const float abv = ab[0];

    const int s0i = tid/20,        q0 = tid - 20*s0i;
    const int i1  = tid + 512;
    const int s1i = i1/20,         q1 = i1 - 20*s1i;
    const bool pf1 = (tid < 128);
    float4 xpf0, xpf1;
    {
        const size_t base0 = (size_t)(blockIdx.x*8)*32;
        xpf0 = *(const float4*)&x[(base0 + s0i)*80 + q0*4];
        if (pf1) xpf1 = *(const float4*)&x[(base0 + s1i)*80 + q1*4];
    }

#pragma unroll 1
    for (int tile=0; tile<8; ++tile){
        const int s0 = (blockIdx.x*8 + tile)*32;
        {
            int t = (q0*4)>>4, f = (q0*4)&15;
            f16x4 h4; h4[0]=(f16)xpf0.x; h4[1]=(f16)xpf0.y; h4[2]=(f16)xpf0.z; h4[3]=(f16)xpf0.w;
            *(f16x4*)&xs[t][s0i][f] = h4;
            if (pf1){
                int t1 = (q1*4)>>4, f1 = (q1*4)&15;
                f16x4 g4; g4[0]=(f16)xpf1.x; g4[1]=(f16)xpf1.y; g4[2]=(f16)xpf1.z; g4[3]=(f16)xpf1.w;
                *(f16x4*)&xs[t1][s1i][f1] = g4;
            }
        }
        if (tile < 7){
            const size_t basen = (size_t)(s0 + 32);
            xpf0 = *(const float4*)&x[(basen + s0i)*80 + q0*4];
            if (pf1) xpf1 = *(const float4*)&x[(basen + s1i)*80 + q1*4];
        }
        float hreg[2][4], aacc[2][4], l_[2] = {0.0f, 0.0f};
#pragma unroll
        for (int st=0; st<2; st++)
#pragma unroll
            for (int r=0;r<4;r++){ aacc[st][r]=0.0f; }
        __syncthreads();

        // ---- t = 0 specialized: h==0 -> x-MFMAs only, no hs read/zero ----
        {
            float sp[2];
#pragma unroll
            for (int st=0; st<2; st++){
                f16x8 Bx = *(const f16x8*)&xs[0][st*16+c][quad*8];
                floatx4 ar = {0,0,0,0}, az = {0,0,0,0}, agi = {0,0,0,0};
                ar = MFMA16(Ar[0], Bx, ar);
                az = MFMA16(Az[0], Bx, az);
                agi = MFMA16(Agi, Bx, agi);
                f16x4 h4;
                sp[st] = 0.0f;
#pragma unroll
                for (int r=0;r<4;r++){
                    float hn = gru_fuse(ar[r] + brz_r[r], az[r] + brz_z[r],
                                        agi[r] + b_in[r], b_hn[r], 0.0f);
                    hreg[st][r] = hn; h4[r] = (f16)hn;
                    sp[st] += hn * awr[r];
                }
                *(f16x4*)&hs[0][st*16 + c][w*16 + quad*4] = h4;
            }
#pragma unroll
            for (int st=0; st<2; st++){
                sp[st] += __shfl_xor(sp[st], 16);
                sp[st] += __shfl_xor(sp[st], 32);
            }
            if (lane < 16){ scpart[0][w][lane] = sp[0]; scpart[0][w][16+lane] = sp[1]; }
            __syncthreads();
        }

#pragma unroll 1
        for (int t=1; t<5; ++t){
            const int rp = (t&1)^1, wp = t&1;
            f16x8 Bx[2], Bh[2][4];
#pragma unroll
            for (int st=0; st<2; st++){
                Bx[st] = *(const f16x8*)&xs[t][st*16+c][quad*8];
#pragma unroll
                for (int i=0;i<4;i++)
                    Bh[st][i] = *(const f16x8*)&hs[rp][st*16+c][i*32+quad*8];
            }
            // lagged attention: apply step t-1's weight to h_{t-1}
            {
#pragma unroll
                for (int st=0; st<2; st++){
                    float sc = abv;
#pragma unroll
                    for (int ww=0; ww<8; ww++) sc += scpart[rp][ww][st*16+c];
                    float e = __expf(sc);
                    l_[st] += e;
#pragma unroll
                    for (int r=0;r<4;r++) aacc[st][r] += e*hreg[st][r];
                }
            }
            float sp[2];
#pragma unroll
            for (int st=0; st<2; st++){
                floatx4 ar = {0,0,0,0}, az = {0,0,0,0}, agi = {0,0,0,0}, agh = {0,0,0,0};
                ar = MFMA16(Ar[0], Bx[st], ar);
                az = MFMA16(Az[0], Bx[st], az);
                agi = MFMA16(Agi, Bx[st], agi);
#pragma unroll
                for (int i=0;i<4;i++){
                    ar = MFMA16(Ar[1+i], Bh[st][i], ar);
                    az = MFMA16(Az[1+i], Bh[st][i], az);
                    agh = MFMA16(Agh[i], Bh[st][i], agh);
                }
                f16x4 h4;
                sp[st] = 0.0f;
#pragma unroll
                for (int r=0;r<4;r++){
                    float hn = gru_fuse(ar[r] + brz_r[r], az[r] + brz_z[r],
                                        agi[r] + b_in[r], agh[r] + b_hn[r], hreg[st][r]);
                    hreg[st][r] = hn; h4[r] = (f16)hn;
                    sp[st] += hn * awr[r];
                }
                *(f16x4*)&hs[wp][st*16 + c][w*16 + quad*4] = h4;
            }
#pragma unroll
            for (int st=0; st<2; st++){
                sp[st] += __shfl_xor(sp[st], 16);
                sp[st] += __shfl_xor(sp[st], 32);
            }
            if (lane < 16){ scpart[wp][w][lane] = sp[0]; scpart[wp][w][16+lane] = sp[1]; }
            __syncthreads();
        }
        // drain — DIRECT global store (R15)
#pragma unroll
        for (int st=0; st<2; st++){
            float sc = abv;
#pragma unroll
            for (int ww=0; ww<8; ww++) sc += scpart[0][ww][st*16+c];
            float e = __expf(sc);
            l_[st] += e;
            float inv = rcpf(l_[st]);
            f16x4 h4;
#pragma unroll
            for (int r=0;r<4;r++) h4[r] = (f16)((aacc[st][r] + e*hreg[st][r])*inv);
            *(f16x4*)&out[(size_t)(s0 + st*16 + c)*128 + w*16 + quad*4] = h4;
        }
    }
}

// ---------------------------------------------------------------------------
// Merged: blocks 0..255 = la GRU+attn (T=32, M=8, t=0 specialized);
// blocks 256..319 = gat_prep (WTp fragment-packed loads).
// ---------------------------------------------------------------------------
__global__ __launch_bounds__(512,2) void gru_la_gatprep(
    const f16* __restrict__ xseq, const f16* __restrict__ Wcat,
    const float* __restrict__ bih, const float* __restrict__ bhh,
    const float* __restrict__ aw, const float* __restrict__ ab,
    f16* __restrict__ out,
    const f16* __restrict__ WTp, const float* __restrict__ gia,
    const int* __restrict__ memflat,
    f16* __restrict__ Whs, float* __restrict__ ers, float* __restrict__ el)
{
    __shared__ __align__(16) f16 xs[2][16][136];
    __shared__ __align__(16) f16 hs[2][16][136];
    __shared__ float scpart[2][8][16];
    __shared__ __align__(16) float tbuf[32][132];
    __shared__ int rows[32];
    const int tid = threadIdx.x, w = tid>>6, lane = tid&63;
    const int c = lane&15, quad = lane>>4;

    if (blockIdx.x >= 256){
        // ---------------- gat_prep (8 waves, 1 jb per wave) ----------------
        const int p0 = (blockIdx.x-256)*32;
        if (tid < 32) rows[tid] = memflat[p0 + tid];
        __syncthreads();
        f16x8 A[2][4];
#pragma unroll
        for (int mt=0;mt<2;mt++)
#pragma unroll
            for (int kb=0;kb<4;kb++)
                A[mt][kb] = *(const f16x8*)&xseq[((size_t)rows[mt*16+c]*32 + 31)*128 + kb*32 + quad*8];
        {
            f16x8 B[4];
#pragma unroll
            for (int kb=0;kb<4;kb++)
                B[kb] = *(const f16x8*)&WTp[(((size_t)(w*4+kb))*64 + lane)*8];
            floatx4 acc[2] = {{0,0,0,0},{0,0,0,0}};
#pragma unroll
            for (int kb=0;kb<4;kb++){
                acc[0] = MFMA16(A[0][kb], B[kb], acc[0]);
                acc[1] = MFMA16(A[1][kb], B[kb], acc[1]);
            }
#pragma unroll
            for (int mt=0;mt<2;mt++)
#pragma unroll
                for (int r=0;r<4;r++)
                    tbuf[mt*16 + quad*4 + r][w*16 + c] = acc[mt][r];
        }
        __syncthreads();
        for (int i=tid; i<1024; i+=512){
            int s = i>>5, p = i&31;
            float4 v = *(const float4*)&tbuf[s][p*4];
            f16x4 h4; h4[0]=(f16)v.x; h4[1]=(f16)v.y; h4[2]=(f16)v.z; h4[3]=(f16)v.w;
            *(f16x4*)&Whs[(size_t)(p0+s)*128 + p*4] = h4;
        }
        for (int k=0; k<4; k++){
            int row = w*4 + k;
            float w0 = tbuf[row][lane], w1 = tbuf[row][64+lane];
            float v1 = w0*gia[lane]     + w1*gia[64+lane];
            float v2 = w0*gia[128+lane] + w1*gia[192+lane];
#pragma unroll
            for (int off=32; off; off>>=1){ v1 += __shfl_down(v1,off); v2 += __shfl_down(v2,off); }
            if (lane==0){ el[rows[row]] = v1; ers[p0+row] = v2; }
        }
        return;
    }
    // ------------------------------ gru_la ------------------------------
    const int s0 = blockIdx.x*8;
    if (tid < 128){
        int s = tid>>4, p = tid&15;
        *(f16x8*)&xs[0][s][p*8] = *(const f16x8*)&xseq[((size_t)(s0+s)*32 + 0)*128 + p*8];
    }
    const int jrow = w*16 + c;
    f16x8 Ar[8], Az[8], Agi[4], Agh[4];
#pragma unroll
    for (int kb=0;kb<8;kb++){
        Ar[kb] = *(const f16x8*)&Wcat[(size_t)(jrow)*256 + kb*32 + quad*8];
        Az[kb] = *(const f16x8*)&Wcat[(size_t)(128+jrow)*256 + kb*32 + quad*8];
    }
#pragma unroll
    for (int i=0;i<4;i++){
        Agi[i] = *(const f16x8*)&Wcat[(size_t)(256+jrow)*256 + i*32 + quad*8];
        Agh[i] = *(const f16x8*)&Wcat[(size_t)(384+jrow)*256 + 128 + i*32 + quad*8];
    }
    float brz_r[4], brz_z[4], b_in[4], b_hn[4], awr[4];
#pragma unroll
    for (int r=0;r<4;r++){
        int j = w*16 + quad*4 + r;
        brz_r[r] = bih[j] + bhh[j];
        brz_z[r] = bih[128+j] + bhh[128+j];
        b_in[r] = bih[256+j]; b_hn[r] = bhh[256+j];
        awr[r] = aw[j];
    }
    const float abv = ab[0];
    float hreg[4] = {0,0,0,0}, aacc[4] = {0,0,0,0}, l_ = 0.0f;
    __syncthreads();

    // ---- t = 0 specialized: h==0 -> x-MFMAs only ----
    {
        f16x8 Bx[4];
#pragma unroll
        for (int i=0;i<4;i++) Bx[i] = *(const f16x8*)&xs[0][c][i*32+quad*8];
        f16x8 xstage;
        if (tid < 128){
            int s = tid>>4, p = tid&15;
            xstage = *(const f16x8*)&xseq[((size_t)(s0+s)*32 + 1)*128 + p*8];
        }
        floatx4 ar = {0,0,0,0}, az = {0,0,0,0}, agi = {0,0,0,0};
#pragma unroll
        for (int i=0;i<4;i++){
            ar  = MFMA16(Ar[i],  Bx[i], ar);
            az  = MFMA16(Az[i],  Bx[i], az);
            agi = MFMA16(Agi[i], Bx[i], agi);
        }
        f16x4 h4;
        float sp = 0.0f;
#pragma unroll
        for (int r=0;r<4;r++){
            float hn = gru_fuse(ar[r] + brz_r[r], az[r] + brz_z[r],
                                agi[r] + b_in[r], b_hn[r], 0.0f);
            hreg[r] = hn; h4[r] = (f16)hn;
            sp += hn * awr[r];
        }
        *(f16x4*)&hs[0][c][w*16 + quad*4] = h4;
        if (tid < 128){
            int s = tid>>4, p = tid&15;
            *(f16x8*)&xs[1][s][p*8] = xstage;
        }
        sp += __shfl_xor(sp, 16);
        sp += __shfl_xor(sp, 32);
        if (lane < 16) scpart[0][w][lane] = sp;
        __syncthreads();
    }

#pragma unroll 1
    for (int t=1; t<32; ++t){
        const int rp = (t&1)^1, wp = t&1, xp = t&1;
        f16x8 Bx[4], Bh[4];
#pragma unroll
        for (int i=0;i<4;i++){
            Bx[i] = *(const f16x8*)&xs[xp][c][i*32+quad*8];
            Bh[i] = *(const f16x8*)&hs[rp][c][i*32+quad*8];
        }
        f16x8 xstage;
        const bool do_stage = (t < 31) && (tid < 128);
        if (do_stage){
            int s = tid>>4, p = tid&15;
            xstage = *(const f16x8*)&xseq[((size_t)(s0+s)*32 + t+1)*128 + p*8];
        }
        {
            float sc = abv;
#pragma unroll
            for (int ww=0; ww<8; ww++) sc += scpart[rp][ww][c];
            float e = __expf(sc);
            l_ += e;
#pragma unroll
            for (int r=0;r<4;r++) aacc[r] += e*hreg[r];
        }
        floatx4 ar = {0,0,0,0}, az = {0,0,0,0}, agi = {0,0,0,0}, agh = {0,0,0,0};
#pragma unroll
        for (int i=0;i<4;i++){
            ar = MFMA16(Ar[i], Bx[i], ar);
            az = MFMA16(Az[i], Bx[i], az);
            agi = MFMA16(Agi[i], Bx[i], agi);
        }
#pragma unroll
        for (int i=0;i<4;i++){
            ar = MFMA16(Ar[4+i], Bh[i], ar);
            az = MFMA16(Az[4+i], Bh[i], az);
            agh = MFMA16(Agh[i], Bh[i], agh);
        }
        f16x4 h4;
        float sp = 0.0f;
#pragma unroll
        for (int r=0;r<4;r++){
            float hn = gru_fuse(ar[r] + brz_r[r], az[r] + brz_z[r],
                                agi[r] + b_in[r], agh[r] + b_hn[r], hreg[r]);
            hreg[r] = hn; h4[r] = (f16)hn;
            sp += hn * awr[r];
        }
        *(f16x4*)&hs[wp][c][w*16 + quad*4] = h4;
        if (do_stage){
            int s = tid>>4, p = tid&15;
            *(f16x8*)&xs[xp^1][s][p*8] = xstage;
        }
        sp += __shfl_xor(sp, 16);
        sp += __shfl_xor(sp, 32);
        if (lane < 16) scpart[wp][w][lane] = sp;
        __syncthreads();
    }
    // drain (t=31 wrote scpart[1])
    {
        float sc = abv;
#pragma unroll
        for (int ww=0; ww<8; ww++) sc += scpart[1][ww][c];
        float e = __expf(sc);
        l_ += e;
        float inv = rcpf(l_);
        f16x4 h4;
#pragma unroll
        for (int r=0;r<4;r++) h4[r] = (f16)((aacc[r] + e*hreg[r])*inv);
        if (c < 8)
            *(f16x4*)&out[(size_t)(s0 + c)*128 + w*16 + quad*4] = h4;
    }
}

// ---------------------------------------------------------------------------
// GAT intra, member-list. One wave per row; streams sorted f16 Wh.
// R16: f16x2-vectorized Whs loads/stores (lane owns cols 2*lane, 2*lane+1).
// ---------------------------------------------------------------------------
__global__ __launch_bounds__(256) void gat_intra_mem_kernel(
    const f16* __restrict__ Whs, const float* __restrict__ ers,
    const float* __restrict__ el, const int* __restrict__ sec,
    const int* __restrict__ cnt, const int* __restrict__ base,
    f16* __restrict__ outp, int S)
{
    int wave = threadIdx.x>>6, lane = threadIdx.x&63;
    int i = blockIdx.x*4 + wave;
    if (i>=S) return;
    int g = sec[i];
    int n = cnt[g], b = base[g];
    float eli = el[i];
    float m = -INFINITY;
    for (int jj=lane; jj<n; jj+=64){
        float v = eli + ers[b+jj]; v = v>0.f? v : LRELU_A*v;
        m = fmaxf(m, v);
    }
#pragma unroll
    for (int off=32; off; off>>=1) m = fmaxf(m, __shfl_xor(m, off));
    float l = 0.f, c0=0.f, c1=0.f;
#pragma unroll 8
    for (int jj=0; jj<n; jj++){
        float v = eli + ers[b+jj]; v = v>0.f? v : LRELU_A*v;
        float p = __expf(v-m);
        l += p;
        f16x2 wv = *(const f16x2*)&Whs[(size_t)(b+jj)*128 + lane*2];
        c0 += p*(float)wv[0];
        c1 += p*(float)wv[1];
    }
    float il = rcpf(l);
    c0 *= il; c1 *= il;
    f16x2 o;
    o[0] = (f16)(c0>0.f? c0 : expm1f(c0));
    o[1] = (f16)(c1>0.f? c1 : expm1f(c1));
    *(f16x2*)&outp[(size_t)i*128 + lane*2] = o;
}

// ---------------------------------------------------------------------------
// lg: T=1 GRU via MFMA; B from ggp (fragment-packed f16).
// R16: 128 blocks (16 rows each, mt-dim removed) — halves per-block serial
// chain for this latency-bound 1/4-of-CUs kernel. Per-output math identical.
// ---------------------------------------------------------------------------
__global__ __launch_bounds__(256) void lg_mfma(
    const f16* __restrict__ intra16, const f16* __restrict__ ggp,
    const float* __restrict__ bih, const float* __restrict__ bhh,
    const int* __restrict__ pos,
    f16* __restrict__ lgout, f16* __restrict__ lgs)
{
    __shared__ __align__(16) f16 tbuf[16][136];
    const int tid = threadIdx.x, w = tid>>6, lane = tid&63;
    const int c = lane&15, quad = lane>>4;
    const int s0 = blockIdx.x*16;
    f16x8 A[4];
#pragma unroll
    for (int kb=0;kb<4;kb++)
        A[kb] = *(const f16x8*)&intra16[(size_t)(s0+c)*128 + kb*32 + quad*8];
#pragma unroll
    for (int i=0;i<2;i++){
        int jb = w*2 + i;
        int j = jb*16 + c;
        f16x8 Br[4], Bz[4], Bn[4];
#pragma unroll
        for (int kb=0;kb<4;kb++){
            Br[kb] = *(const f16x8*)&ggp[(((size_t)((0*8+jb)*4+kb))*64 + lane)*8];
            Bz[kb] = *(const f16x8*)&ggp[(((size_t)((1*8+jb)*4+kb))*64 + lane)*8];
            Bn[kb] = *(const f16x8*)&ggp[(((size_t)((2*8+jb)*4+kb))*64 + lane)*8];
        }
        float b_r = bih[j] + bhh[j];
        float b_z = bih[128+j] + bhh[128+j];
        float b_i = bih[256+j], b_h = bhh[256+j];
        floatx4 ar = {0,0,0,0}, az = {0,0,0,0}, an = {0,0,0,0};
#pragma unroll
        for (int kb=0;kb<4;kb++){
            ar = MFMA16(A[kb], Br[kb], ar);
            az = MFMA16(A[kb], Bz[kb], az);
            an = MFMA16(A[kb], Bn[kb], an);
        }
#pragma unroll
        for (int r=0;r<4;r++){
            float Er = __expf(-(ar[r] + b_r));
            float rg = rcpf(1.0f + Er);
            float En = __expf(2.0f*(an[r] + b_i + rg*b_h));
            float Ez = __expf(-(az[r] + b_z));
            float v = (En - 1.0f)*Ez * rcpf((En + 1.0f)*(1.0f + Ez));
            tbuf[quad*4 + r][j] = (f16)v;
        }
    }
    __syncthreads();
    {
        int s = tid>>4, p = tid&15;
        f16x8 v = *(const f16x8*)&tbuf[s][p*8];
        *(f16x8*)&lgout[(size_t)(s0+s)*128 + p*8] = v;
        *(f16x8*)&lgs[(size_t)pos[s0+s]*128 + p*8] = v;
    }
}

// ---------------------------------------------------------------------------
// Fused tail: sector means (sorted lgs, contiguous) + inter GAT.
// Phase B via MFMA with gep (fragment-packed).
// ---------------------------------------------------------------------------
__global__ __launch_bounds__(1024) void gat_inter_fused(
    const f16* __restrict__ lgs, const int* __restrict__ cnt,
    const int* __restrict__ base, const int* __restrict__ adj,
    const f16* __restrict__ gep, const float* __restrict__ a,
    float* __restrict__ outp)
{
    __shared__ __align__(16) float hs[16][132];
    __shared__ __align__(16) float Whs[16][132];
    __shared__ float el[16], er[16];
    __shared__ float att[16][16];
    const int tid = threadIdx.x, w = tid>>6, lane = tid&63;
    const int c = lane&15, quad = lane>>4;

    // Phase A: wave w sums sector w over its contiguous sorted rows.
    {
        int n = cnt[w], b = base[w];
        const int rowoff = lane>>4;
        const int colb = (lane&15)*8;
        float acc[8] = {0,0,0,0,0,0,0,0};
        for (int r = rowoff; r < n; r += 4){
            f16x8 v = *(const f16x8*)&lgs[(size_t)(b+r)*128 + colb];
#pragma unroll
            for (int k=0;k<8;k++) acc[k] += (float)v[k];
        }
#pragma unroll
        for (int k=0;k<8;k++){
            acc[k] += __shfl_xor(acc[k], 16);
            acc[k] += __shfl_xor(acc[k], 32);
        }
        if (lane < 16){
            float inv = rcpf(fmaxf((float)n, 1.0f));
#pragma unroll
            for (int k=0;k<8;k++) hs[w][colb+k] = acc[k]*inv;
        }
    }
    __syncthreads();
    // Phase B (MFMA): Whs = hs @ geW; wave w<8 computes column tile w.
    if (w < 8){
        f16x8 A[4], B[4];
#pragma unroll
        for (int kb=0;kb<4;kb++){
            A[kb] = load_cvt8(&hs[c][kb*32 + quad*8]);
            B[kb] = *(const f16x8*)&gep[(((size_t)(w*4+kb))*64 + lane)*8];
        }
        floatx4 acc = {0,0,0,0};
#pragma unroll
        for (int kb=0;kb<4;kb++) acc = MFMA16(A[kb], B[kb], acc);
#pragma unroll
        for (int r=0;r<4;r++) Whs[quad*4 + r][w*16 + c] = acc[r];
    }
    __syncthreads();
    // Phase C: el/er — wave w reduces sector w; lanes 0-31: el, 32-63: er.
    {
        int half = lane>>5, l = lane&31;
        const float* av = a + half*128;
        float acc2 = 0.f;
#pragma unroll
        for (int k=0;k<4;k++) acc2 += Whs[w][l+32*k]*av[l+32*k];
#pragma unroll
        for (int off=1; off<32; off<<=1) acc2 += __shfl_xor(acc2, off);
        if (l==0){ if (half) er[w]=acc2; else el[w]=acc2; }
    }
    __syncthreads();
    // Phase D: 16x16 masked softmax
    if (tid<16){
        int i=tid; float m=NEGBIG; float e[16];
        for(int j=0;j<16;j++){
            float v = el[i]+er[j]; v = v>0.f? v : LRELU_A*v;
            e[j] = (adj[i*16+j]>0)? v : NEGBIG;
            m = fmaxf(m,e[j]);
        }
        float l=0.f;
        for(int j=0;j<16;j++){ float p=__expf(e[j]-m); att[i][j]=p; l+=p; }
        float il = rcpf(l);
        for(int j=0;j<16;j++) att[i][j] *= il;
    }
    __syncthreads();
    // Phase E: att @ Whs + ELU
#pragma unroll
    for (int i=0;i<2;i++){
        int idx=i*1024+tid; int o=idx&127, s=idx>>7;
        float acc=0.f;
#pragma unroll
        for(int j=0;j<16;j++) acc += att[s][j]*Whs[j][o];
        outp[s*128+o] = acc>0.f? acc : expm1f(acc);
    }
}

// ---------------------------------------------------------------------------
// fused = [lg|la|sec_ps] @ fw + fb, then both heads. B from fwp (packed).
// R16: 128 blocks (16 rows each, mt-dim removed) — halves per-block serial
// chain. Per-output math identical.
// ---------------------------------------------------------------------------
__global__ __launch_bounds__(256) void fused_mfma(
    const f16* __restrict__ lg16, const f16* __restrict__ la16,
    const float* __restrict__ seco, const int* __restrict__ sec,
    const f16* __restrict__ fwp,
    const float* __restrict__ fb, const float* __restrict__ rw,
    const float* __restrict__ rb, const float* __restrict__ mw,
    const float* __restrict__ mb, float* __restrict__ outp)
{
    __shared__ float rpart[4][16], mpart[4][16];
    const int tid = threadIdx.x, w = tid>>6, lane = tid&63;
    const int c = lane&15, quad = lane>>4;
    const int s0 = blockIdx.x*16;
    f16x8 A[12];
    {
        int row = s0 + c;
        int g = sec[row];
#pragma unroll
        for (int kb=0;kb<4;kb++){
            A[kb]   = *(const f16x8*)&lg16[(size_t)row*128 + kb*32 + quad*8];
            A[4+kb] = *(const f16x8*)&la16[(size_t)row*128 + kb*32 + quad*8];
            A[8+kb] = load_cvt8(&seco[(size_t)g*128 + kb*32 + quad*8]);
        }
    }
    float rsum[4] = {0,0,0,0};
    float msum[4] = {0,0,0,0};
#pragma unroll
    for (int i=0;i<2;i++){
        int jb = w*2 + i;
        int col = jb*16 + c;
        f16x8 B[12];
#pragma unroll
        for (int kb=0;kb<12;kb++)
            B[kb] = *(const f16x8*)&fwp[(((size_t)(jb*12+kb))*64 + lane)*8];
        floatx4 acc = {0,0,0,0};
#pragma unroll
        for (int kb=0;kb<12;kb++)
            acc = MFMA16(A[kb], B[kb], acc);
        float fbv = fb[col], rwv = rw[col], mwv = mw[col];
#pragma unroll
        for (int r=0;r<4;r++){
            float fu = acc[r] + fbv;
            rsum[r] += fu*rwv;
            msum[r] += fu*mwv;
        }
    }
#pragma unroll
    for (int r=0;r<4;r++){
#pragma unroll
        for (int off=1; off<16; off<<=1){
            rsum[r] += __shfl_xor(rsum[r], off);
            msum[r] += __shfl_xor(msum[r], off);
        }
        if (c==0){
            rpart[w][quad*4 + r] = rsum[r];
            mpart[w][quad*4 + r] = msum[r];
        }
    }
    __syncthreads();
    if (tid < 16){
        int s = tid;
        float rs = rb[0], ms = mb[0];
#pragma unroll
        for (int ww=0; ww<4; ww++){ rs += rpart[ww][s]; ms += mpart[ww][s]; }
        outp[s0+s] = rs;
        outp[2048 + s0 + s] = sigm(ms);
    }
}

extern "C" void kernel_launch(void* const* d_in, const int* in_sizes, int n_in,
                              void* d_out, int out_size, void* d_ws, size_t ws_size,
                              hipStream_t stream) {
    const float* sf    = (const float*)d_in[0];
    const int*   sec   = (const int*)  d_in[1];
    const int*   adj   = (const int*)  d_in[2];
    const float* g1Wih = (const float*)d_in[3];
    const float* g1Whh = (const float*)d_in[4];
    const float* g1bih = (const float*)d_in[5];
    const float* g1bhh = (const float*)d_in[6];
    const float* a1w   = (const float*)d_in[7];
    const float* a1b   = (const float*)d_in[8];
    const float* giW   = (const float*)d_in[9];
    const float* gia   = (const float*)d_in[10];
    const float* ggWih = (const float*)d_in[11];
    const float* ggbih = (const float*)d_in[13];
    const float* ggbhh = (const float*)d_in[14];
    const float* gaWih = (const float*)d_in[17];
    const float* gaWhh = (const float*)d_in[18];
    const float* gabih = (const float*)d_in[19];
    const float* gabhh = (const float*)d_in[20];
    const float* aaw   = (const float*)d_in[21];
    const float* aab   = (const float*)d_in[22];
    const float* geW   = (const float*)d_in[23];
    const float* gea   = (const float*)d_in[24];
    const float* fw    = (const float*)d_in[25];
    const float* fb    = (const float*)d_in[26];
    const float* rw    = (const float*)d_in[27];
    const float* rb    = (const float*)d_in[28];
    const float* mw    = (const float*)d_in[29];
    const float* mb    = (const float*)d_in[30];

    char* p = (char*)d_ws;
    f16*   shrt16 = (f16*)p;   p += (size_t)65536*128*2;
    f16*   intra16= (f16*)p;   p += (size_t)262144*2;
    f16*   lg16   = (f16*)p;   p += (size_t)262144*2;
    f16*   la16   = (f16*)p;   p += (size_t)262144*2;
    f16*   Whs    = (f16*)p;   p += (size_t)262144*2;
    f16*   lgs    = (f16*)p;   p += (size_t)262144*2;
    f16*   Wcat1  = (f16*)p;   p += (size_t)512*160*2;
    f16*   WcatA  = (f16*)p;   p += (size_t)512*256*2;
    f16*   WTp    = (f16*)p;   p += (size_t)16384*2;
    f16*   gep    = (f16*)p;   p += (size_t)16384*2;
    f16*   fwp    = (f16*)p;   p += (size_t)49152*2;
    f16*   ggp    = (f16*)p;   p += (size_t)49152*2;
    float* el     = (float*)p; p += 2048*4;
    float* ers    = (float*)p; p += 2048*4;
    float* seco   = (float*)p; p += 2048*4;
    int*   memflat= (int*)p;   p += 2048*4;
    int*   pos    = (int*)p;   p += 2048*4;
    int*   cnt    = (int*)p;   p += 16*4;
    int*   basep  = (int*)p;   p += 16*4;

    // 0. prep1: only Wcat1 (gru_short's sole dependency)
    prep1_kernel<<<160,256,0,stream>>>(g1Wih, g1Whh, Wcat1);
    // 1. short GRU+attn (blocks 0..255) || prep2 (blocks 256..768)
    gru_short<<<769,512,0,stream>>>(sf, Wcat1, g1bih, g1bhh, a1w, a1b, shrt16,
                                    gaWih, gaWhh, giW, fw, geW, ggWih, sec,
                                    WcatA, WTp, fwp, gep, ggp,
                                    memflat, pos, cnt, basep);
    // 2. la GRU+attn (t=0 specialized) || gat_prep — merged
    gru_la_gatprep<<<320,512,0,stream>>>(shrt16, WcatA, gabih, gabhh, aaw, aab, la16,
                                         WTp, gia, memflat, Whs, ers, el);
    // 3. intra-sector GAT (f16x2 vectorized)
    gat_intra_mem_kernel<<<512,256,0,stream>>>(Whs, ers, el, sec, cnt, basep, intra16, 2048);
    // 4. lg — 128 blocks (halved per-block chain)
    lg_mfma<<<128,256,0,stream>>>(intra16, ggp, ggbih, ggbhh, pos, lg16, lgs);
    // 5+6. fused sector means + inter-sector GAT
    gat_inter_fused<<<1,1024,0,stream>>>(lgs, cnt, basep, adj, gep, gea, seco);
    // 7. fusion + heads — 128 blocks (halved per-block chain)
    fused_mfma<<<128,256,0,stream>>>(lg16, la16, seco, sec, fwp, fb, rw, rb, mw, mb, (float*)d_out);
}